// Round 9
// baseline (698.631 us; speedup 1.0000x reference)
//
#include <hip/hip_runtime.h>
#include <cstdint>
#include <cstddef>

#define DEV_INLINE __device__ __forceinline__

static constexpr float EPS = 1e-5f;

DEV_INLINE float sigmoidf_(float x) { return 1.0f / (1.0f + __expf(-x)); }
DEV_INLINE float siluf_(float x) { return x * sigmoidf_(x); }
DEV_INLINE float softplus_fast(float x) {
    return fmaxf(x, 0.0f) + __logf(1.0f + __expf(-fabsf(x)));
}
DEV_INLINE unsigned short f2bf(float x) {   // RNE f32 -> bf16
    unsigned u = __builtin_bit_cast(unsigned, x);
    u += 0x7FFFu + ((u >> 16) & 1u);
    return (unsigned short)(u >> 16);
}
DEV_INLINE float bf2f(unsigned short s) {
    unsigned u = ((unsigned)s) << 16;
    return __builtin_bit_cast(float, u);
}

typedef __attribute__((ext_vector_type(8))) short bf16x8;
typedef __attribute__((ext_vector_type(4))) float f32x4;

DEV_INLINE void gload16(const unsigned short* src, char* ldsdst) {
    __builtin_amdgcn_global_load_lds(
        (const __attribute__((address_space(1))) unsigned int*)src,
        (__attribute__((address_space(3))) unsigned int*)ldsdst, 16, 0, 0);
}

DEV_INLINE void cvt8(const float* __restrict__ s, unsigned short* __restrict__ d, int t) {
    float4 f0 = *(const float4*)(s + (size_t)t * 8);
    float4 f1 = *(const float4*)(s + (size_t)t * 8 + 4);
    union { unsigned short u[8]; uint4 v; } pk;
    pk.u[0] = f2bf(f0.x); pk.u[1] = f2bf(f0.y); pk.u[2] = f2bf(f0.z); pk.u[3] = f2bf(f0.w);
    pk.u[4] = f2bf(f1.x); pk.u[5] = f2bf(f1.y); pk.u[6] = f2bf(f1.z); pk.u[7] = f2bf(f1.w);
    *(uint4*)(d + (size_t)t * 8) = pk.v;
}

// ---------------------------------------------------------------------------
// One-shot prep: motion cvt | w_up transpose | w1 | w2 | 4x layer weights.
// ---------------------------------------------------------------------------
__global__ __launch_bounds__(256) void prep_all(
    const float* __restrict__ motion, const float* __restrict__ wup,
    const float* __restrict__ w1, const float* __restrict__ w2,
    const float* __restrict__ in_proj_w, const float* __restrict__ out_proj_w,
    const float* __restrict__ x_proj_w, const float* __restrict__ dt_proj_w,
    unsigned short* __restrict__ mbf, unsigned short* __restrict__ wupT,
    unsigned short* __restrict__ w1b, unsigned short* __restrict__ w2b,
    unsigned short* __restrict__ lw)
{
    int bid = (int)blockIdx.x, tid = (int)threadIdx.x;
    if (bid < 1024) {
        cvt8(motion, mbf, bid * 256 + tid);
    } else if (bid < 2048) {
        int t = (bid - 1024) * 256 + tid;
        int c = t >> 9, o = t & 511;
        float2 v = *(const float2*)(wup + (size_t)t * 2);
        wupT[(size_t)o * 512 + c] = f2bf(v.x);
        wupT[262144 + (size_t)o * 512 + c] = f2bf(v.y);
    } else if (bid < 2304) {
        cvt8(w1, w1b, (bid - 2048) * 256 + tid);
    } else if (bid < 2432) {
        cvt8(w2, w2b, (bid - 2304) * 256 + tid);
    } else {
        int r = bid - 2432;
        int layer = r / 816;
        int lb = r - layer * 816;
        unsigned short* base = lw + (size_t)layer * 1671168;
        if (lb < 512) {
            cvt8(in_proj_w + (size_t)layer * 1048576, base, lb * 256 + tid);
        } else if (lb < 768) {
            cvt8(out_proj_w + (size_t)layer * 524288, base + 1048576,
                 (lb - 512) * 256 + tid);
        } else if (lb < 800) {
            cvt8(x_proj_w + (size_t)layer * 65536, base + 1572864,
                 (lb - 768) * 256 + tid);
        } else {
            cvt8(dt_proj_w + (size_t)layer * 32768, base + 1638400,
                 (lb - 800) * 256 + tid);
        }
    }
}

// ---------------------------------------------------------------------------
// MFMA GEMM 128x128
// ---------------------------------------------------------------------------
template <int ACT, bool ACC, bool EMBED, bool OBF>
__global__ __launch_bounds__(256) void gemm_mfma(
    const unsigned short* __restrict__ A, int lda,
    const unsigned short* __restrict__ W, int ldw,
    void* __restrict__ Cv, int ldc, int N, int K, int gx,
    const float* __restrict__ bias, const float* __restrict__ embed)
{
    __shared__ unsigned short Asm[2][128 * 64];
    __shared__ unsigned short Wsm[2][128 * 64];
    const int tid = (int)threadIdx.x;
    const int lane = tid & 63;
    const int wv = tid >> 6;
    const int wm = wv >> 1, wn = wv & 1;

    const int nwg = (int)gridDim.x;
    const int lin = (int)blockIdx.x;
    const int logical = (lin & 7) * (nwg >> 3) + (lin >> 3);
    const int by = logical / gx;
    const int bx = logical - by * gx;
    const int bm = by * 128, bn = bx * 128;

    f32x4 acc[4][4] = {};
    const int l8 = lane >> 3;
    const int wc = lane & 7;
    const int wcg = wc ^ l8;
    const int NT = K >> 6;

    {
        char* aB = (char*)Asm[0];
        char* bB = (char*)Wsm[0];
#pragma unroll
        for (int i = 0; i < 4; ++i) {
            int rb = (i * 4 + wv) * 8;
            gload16(W + (size_t)(bn + rb + l8) * ldw + wcg * 8, bB + rb * 128);
            gload16(A + (size_t)(bm + rb + l8) * lda + wcg * 8, aB + rb * 128);
        }
    }
    __syncthreads();

    for (int t = 0; t < NT; ++t) {
        const int cur = t & 1;
        if (t + 1 < NT) {
            const int k1 = (t + 1) << 6;
            char* aB = (char*)Asm[cur ^ 1];
            char* bB = (char*)Wsm[cur ^ 1];
#pragma unroll
            for (int i = 0; i < 4; ++i) {
                int rb = (i * 4 + wv) * 8;
                gload16(W + (size_t)(bn + rb + l8) * ldw + k1 + wcg * 8, bB + rb * 128);
                gload16(A + (size_t)(bm + rb + l8) * lda + k1 + wcg * 8, aB + rb * 128);
            }
        }
        const char* aB = (const char*)Asm[cur];
        const char* bB = (const char*)Wsm[cur];
        const int rA = wm * 64 + (lane & 15);
        const int rB = wn * 64 + (lane & 15);
        const int q = lane >> 4;
#pragma unroll
        for (int kk = 0; kk < 2; ++kk) {
            bf16x8 af[4], bfr[4];
#pragma unroll
            for (int mi = 0; mi < 4; ++mi) {
                int row = rA + mi * 16;
                int ch = (kk * 4 + q) ^ (row & 7);
                af[mi] = *(const bf16x8*)(aB + row * 128 + ch * 16);
            }
#pragma unroll
            for (int ni = 0; ni < 4; ++ni) {
                int row = rB + ni * 16;
                int ch = (kk * 4 + q) ^ (row & 7);
                bfr[ni] = *(const bf16x8*)(bB + row * 128 + ch * 16);
            }
#pragma unroll
            for (int mi = 0; mi < 4; ++mi)
#pragma unroll
                for (int ni = 0; ni < 4; ++ni)
                    acc[mi][ni] = __builtin_amdgcn_mfma_f32_16x16x32_bf16(
                        af[mi], bfr[ni], acc[mi][ni], 0, 0, 0);
        }
        __syncthreads();
    }

    const int cn = lane & 15;
    const int r0 = (lane >> 4) * 4;
    const int eb = EMBED ? (bm >> 10) * N : 0;
#pragma unroll
    for (int ni = 0; ni < 4; ++ni) {
        int col = bn + wn * 64 + ni * 16 + cn;
        float add = bias ? bias[col] : 0.0f;
        if (EMBED) add += embed[eb + col];
#pragma unroll
        for (int mi = 0; mi < 4; ++mi) {
#pragma unroll
            for (int r = 0; r < 4; ++r) {
                int row = bm + wm * 64 + mi * 16 + r0 + r;
                float v = acc[mi][ni][r] + add;
                if (ACT == 1) v = softplus_fast(v);
                if (OBF) {
                    ((unsigned short*)Cv)[(size_t)row * ldc + col] = f2bf(v);
                } else {
                    float* p = (float*)Cv + (size_t)row * ldc + col;
                    if (ACC) *p += v; else *p = v;
                }
            }
        }
    }
}

// ---------------------------------------------------------------------------
// MFMA GEMM 64x64. UPS: upsample epilogue.
// ---------------------------------------------------------------------------
template <int ACT, bool ACC, bool EMBED, bool OBF, bool UPS>
__global__ __launch_bounds__(256) void gemm_mfma64(
    const unsigned short* __restrict__ A, int lda,
    const unsigned short* __restrict__ W, int ldw,
    void* __restrict__ Cv, int ldc, int N, int K, int gx,
    const float* __restrict__ bias, const float* __restrict__ embed)
{
    __shared__ unsigned short Asm[2][64 * 64];
    __shared__ unsigned short Wsm[2][64 * 64];
    const int tid = (int)threadIdx.x;
    const int lane = tid & 63;
    const int wv = tid >> 6;
    const int wm = wv >> 1, wn = wv & 1;

    const int nwg = (int)gridDim.x;
    const int lin = (int)blockIdx.x;
    const int logical = (lin & 7) * (nwg >> 3) + (lin >> 3);
    const int by = logical / gx;
    const int bx = logical - by * gx;
    const int bm = by * 64, bn = bx * 64;

    f32x4 acc[2][2] = {};
    const int l8 = lane >> 3;
    const int wc = lane & 7;
    const int wcg = wc ^ l8;
    const int NT = K >> 6;

    {
        char* aB = (char*)Asm[0];
        char* bB = (char*)Wsm[0];
#pragma unroll
        for (int i = 0; i < 2; ++i) {
            int rb = (i * 4 + wv) * 8;
            gload16(W + (size_t)(bn + rb + l8) * ldw + wcg * 8, bB + rb * 128);
            gload16(A + (size_t)(bm + rb + l8) * lda + wcg * 8, aB + rb * 128);
        }
    }
    __syncthreads();

    for (int t = 0; t < NT; ++t) {
        const int cur = t & 1;
        if (t + 1 < NT) {
            const int k1 = (t + 1) << 6;
            char* aB = (char*)Asm[cur ^ 1];
            char* bB = (char*)Wsm[cur ^ 1];
#pragma unroll
            for (int i = 0; i < 2; ++i) {
                int rb = (i * 4 + wv) * 8;
                gload16(W + (size_t)(bn + rb + l8) * ldw + k1 + wcg * 8, bB + rb * 128);
                gload16(A + (size_t)(bm + rb + l8) * lda + k1 + wcg * 8, aB + rb * 128);
            }
        }
        const char* aB = (const char*)Asm[cur];
        const char* bB = (const char*)Wsm[cur];
        const int rA = wm * 32 + (lane & 15);
        const int rB = wn * 32 + (lane & 15);
        const int q = lane >> 4;
#pragma unroll
        for (int kk = 0; kk < 2; ++kk) {
            bf16x8 af[2], bfr[2];
#pragma unroll
            for (int mi = 0; mi < 2; ++mi) {
                int row = rA + mi * 16;
                int ch = (kk * 4 + q) ^ (row & 7);
                af[mi] = *(const bf16x8*)(aB + row * 128 + ch * 16);
            }
#pragma unroll
            for (int ni = 0; ni < 2; ++ni) {
                int row = rB + ni * 16;
                int ch = (kk * 4 + q) ^ (row & 7);
                bfr[ni] = *(const bf16x8*)(bB + row * 128 + ch * 16);
            }
#pragma unroll
            for (int mi = 0; mi < 2; ++mi)
#pragma unroll
                for (int ni = 0; ni < 2; ++ni)
                    acc[mi][ni] = __builtin_amdgcn_mfma_f32_16x16x32_bf16(
                        af[mi], bfr[ni], acc[mi][ni], 0, 0, 0);
        }
        __syncthreads();
    }

    const int cn = lane & 15;
    const int r0 = (lane >> 4) * 4;
    const int eb = EMBED ? (bm >> 10) * N : 0;
#pragma unroll
    for (int ni = 0; ni < 2; ++ni) {
        int col = bn + wn * 32 + ni * 16 + cn;
        float add = bias ? bias[UPS ? (col & 511) : col] : 0.0f;
        if (EMBED) add += embed[eb + col];
#pragma unroll
        for (int mi = 0; mi < 2; ++mi) {
#pragma unroll
            for (int r = 0; r < 4; ++r) {
                int row = bm + wm * 32 + mi * 16 + r0 + r;
                float v = acc[mi][ni][r] + add;
                if (ACT == 1) v = softplus_fast(v);
                if (UPS) {
                    size_t ad = (size_t)row * 2048 + ((col >> 9) << 10) + (col & 511);
                    ((unsigned short*)Cv)[ad] = f2bf(v);
                } else if (OBF) {
                    ((unsigned short*)Cv)[(size_t)row * ldc + col] = f2bf(v);
                } else {
                    float* p = (float*)Cv + (size_t)row * ldc + col;
                    if (ACC) *p += v; else *p = v;
                }
            }
        }
    }
}

// ---------------------------------------------------------------------------
// dt GEMM: dt[8192,1024] = softplus(dtp[8192,32] @ dtw[1024,32]^T + bias)
// ---------------------------------------------------------------------------
__global__ __launch_bounds__(256) void gemm_dt(
    const unsigned short* __restrict__ xdbc,
    const unsigned short* __restrict__ wdt,
    const float* __restrict__ bias,
    unsigned short* __restrict__ out)
{
    __shared__ unsigned short S[128 * 136];
    const int tid = (int)threadIdx.x;
    const int lane = tid & 63;
    const int wv = tid >> 6;
    const int wm = wv >> 1, wn = wv & 1;

    const int lin = (int)blockIdx.x;
    const int logical = (lin & 7) * 64 + (lin >> 3);
    const int bm = (logical >> 3) * 128;
    const int bn = (logical & 7) * 128;

    const int fr = lane & 15;
    const int q = lane >> 4;

    bf16x8 af[4], wf[4];
#pragma unroll
    for (int mi = 0; mi < 4; ++mi)
        af[mi] = *(const bf16x8*)(xdbc + (size_t)(bm + wm * 64 + mi * 16 + fr) * 64 + q * 8);
#pragma unroll
    for (int ni = 0; ni < 4; ++ni)
        wf[ni] = *(const bf16x8*)(wdt + (size_t)(bn + wn * 64 + ni * 16 + fr) * 32 + q * 8);

    f32x4 acc[4][4] = {};
#pragma unroll
    for (int mi = 0; mi < 4; ++mi)
#pragma unroll
        for (int ni = 0; ni < 4; ++ni)
            acc[mi][ni] = __builtin_amdgcn_mfma_f32_16x16x32_bf16(
                af[mi], wf[ni], acc[mi][ni], 0, 0, 0);

    const int cn = lane & 15;
    const int r0 = (lane >> 4) * 4;
#pragma unroll
    for (int ni = 0; ni < 4; ++ni) {
        int lcol = wn * 64 + ni * 16 + cn;
        float add = bias[bn + lcol];
#pragma unroll
        for (int mi = 0; mi < 4; ++mi) {
#pragma unroll
            for (int r = 0; r < 4; ++r) {
                int lrow = wm * 64 + mi * 16 + r0 + r;
                S[lrow * 136 + lcol] = f2bf(softplus_fast(acc[mi][ni][r] + add));
            }
        }
    }
    __syncthreads();

    const int row = tid >> 1;
    const int half = tid & 1;
    const unsigned short* src = S + row * 136 + half * 64;
    unsigned short* dst = out + (size_t)(bm + row) * 1024 + bn + half * 64;
#pragma unroll
    for (int k = 0; k < 8; ++k) {
        uint4 v = *(const uint4*)(src + k * 8);
        *(uint4*)(dst + k * 8) = v;
    }
}

// ---------------------------------------------------------------------------
// Skinny MFMA GEMM: xdbc[M,64] = u[M,1024] * xpw[64,1024]^T (bf16 out)
// ---------------------------------------------------------------------------
__global__ __launch_bounds__(128) void gemm_xdbc(
    const unsigned short* __restrict__ A,
    const unsigned short* __restrict__ W,
    unsigned short* __restrict__ C)
{
    __shared__ unsigned short Asm[64 * 64];
    __shared__ unsigned short Wsm[64 * 64];
    const int tid = (int)threadIdx.x;
    const int lane = tid & 63;
    const int w = tid >> 6;
    const int bm = blockIdx.x * 64;
    const int l8 = lane >> 3, wc = lane & 7, wcg = wc ^ l8;
    char* aB = (char*)Asm;
    char* bB = (char*)Wsm;

    f32x4 acc[2][4] = {};

    for (int k0 = 0; k0 < 1024; k0 += 64) {
#pragma unroll
        for (int i = 0; i < 4; ++i) {
            int rb = (i * 2 + w) * 8;
            gload16(A + (size_t)(bm + rb + l8) * 1024 + k0 + wcg * 8, aB + rb * 128);
            gload16(W + (size_t)(rb + l8) * 1024 + k0 + wcg * 8, bB + rb * 128);
        }
        __syncthreads();
        const int rA = w * 32 + (lane & 15);
        const int rB = (lane & 15);
        const int q = lane >> 4;
#pragma unroll
        for (int kk = 0; kk < 2; ++kk) {
            bf16x8 af[2], bfr[4];
#pragma unroll
            for (int mi = 0; mi < 2; ++mi) {
                int row = rA + mi * 16;
                int ch = (kk * 4 + q) ^ (row & 7);
                af[mi] = *(const bf16x8*)(aB + row * 128 + ch * 16);
            }
#pragma unroll
            for (int ni = 0; ni < 4; ++ni) {
                int row = rB + ni * 16;
                int ch = (kk * 4 + q) ^ (row & 7);
                bfr[ni] = *(const bf16x8*)(bB + row * 128 + ch * 16);
            }
#pragma unroll
            for (int mi = 0; mi < 2; ++mi)
#pragma unroll
                for (int ni = 0; ni < 4; ++ni)
                    acc[mi][ni] = __builtin_amdgcn_mfma_f32_16x16x32_bf16(
                        af[mi], bfr[ni], acc[mi][ni], 0, 0, 0);
        }
        __syncthreads();
    }
    const int cn = lane & 15;
    const int r0 = (lane >> 4) * 4;
#pragma unroll
    for (int mi = 0; mi < 2; ++mi)
#pragma unroll
        for (int ni = 0; ni < 4; ++ni)
#pragma unroll
            for (int r = 0; r < 4; ++r) {
                int row = bm + w * 32 + mi * 16 + r0 + r;
                C[(size_t)row * 64 + ni * 16 + cn] = f2bf(acc[mi][ni][r]);
            }
}

// ---------------------------------------------------------------------------
__global__ __launch_bounds__(256) void concat_skip(
    const float* __restrict__ skip, unsigned short* __restrict__ x0)
{
    int t = blockIdx.x * 256 + (int)threadIdx.x;
    int row = t >> 6;
    int c8 = (t & 63) << 3;
    const float* s = skip + (size_t)row * 512 + c8;
    float4 f0 = *(const float4*)s;
    float4 f1 = *(const float4*)(s + 4);
    union { unsigned short u[8]; uint4 v; } pk;
    pk.u[0] = f2bf(f0.x); pk.u[1] = f2bf(f0.y); pk.u[2] = f2bf(f0.z); pk.u[3] = f2bf(f0.w);
    pk.u[4] = f2bf(f1.x); pk.u[5] = f2bf(f1.y); pk.u[6] = f2bf(f1.z); pk.u[7] = f2bf(f1.w);
    *(uint4*)(x0 + (size_t)row * 1024 + 512 + c8) = pk.v;
}

// ---------------------------------------------------------------------------
template <bool BFOUT>
__global__ __launch_bounds__(256) void layernorm_k(
    const float* __restrict__ x, void* __restrict__ outp,
    const float* __restrict__ w, const float* __restrict__ b)
{
    const int row = blockIdx.x * 4 + ((int)threadIdx.x >> 6);
    const int lane = (int)threadIdx.x & 63;
    const float* xr = x + (size_t)row * 512;
    float4 v0 = *(const float4*)(xr + lane * 4);
    float4 v1 = *(const float4*)(xr + 256 + lane * 4);
    float s = v0.x + v0.y + v0.z + v0.w + v1.x + v1.y + v1.z + v1.w;
    float q = v0.x*v0.x + v0.y*v0.y + v0.z*v0.z + v0.w*v0.w
            + v1.x*v1.x + v1.y*v1.y + v1.z*v1.z + v1.w*v1.w;
#pragma unroll
    for (int o = 32; o; o >>= 1) {
        s += __shfl_xor(s, o, 64);
        q += __shfl_xor(q, o, 64);
    }
    const float mean = s * (1.0f / 512.0f);
    const float var = q * (1.0f / 512.0f) - mean * mean;
    const float rstd = rsqrtf(var + EPS);
    float4 w0 = *(const float4*)(w + lane * 4);
    float4 w1 = *(const float4*)(w + 256 + lane * 4);
    float4 b0 = *(const float4*)(b + lane * 4);
    float4 b1 = *(const float4*)(b + 256 + lane * 4);
    float4 o0, o1;
    o0.x = (v0.x - mean) * rstd * w0.x + b0.x;
    o0.y = (v0.y - mean) * rstd * w0.y + b0.y;
    o0.z = (v0.z - mean) * rstd * w0.z + b0.z;
    o0.w = (v0.w - mean) * rstd * w0.w + b0.w;
    o1.x = (v1.x - mean) * rstd * w1.x + b1.x;
    o1.y = (v1.y - mean) * rstd * w1.y + b1.y;
    o1.z = (v1.z - mean) * rstd * w1.z + b1.z;
    o1.w = (v1.w - mean) * rstd * w1.w + b1.w;
    if (BFOUT) {
        unsigned short* ob = (unsigned short*)outp + (size_t)row * 512;
        union { unsigned short u[4]; uint2 v; } p0, p1;
        p0.u[0] = f2bf(o0.x); p0.u[1] = f2bf(o0.y); p0.u[2] = f2bf(o0.z); p0.u[3] = f2bf(o0.w);
        p1.u[0] = f2bf(o1.x); p1.u[1] = f2bf(o1.y); p1.u[2] = f2bf(o1.z); p1.u[3] = f2bf(o1.w);
        *(uint2*)(ob + lane * 4) = p0.v;
        *(uint2*)(ob + 256 + lane * 4) = p1.v;
    } else {
        float* orow = (float*)outp + (size_t)row * 512;
        *(float4*)(orow + lane * 4) = o0;
        *(float4*)(orow + 256 + lane * 4) = o1;
    }
}

__global__ __launch_bounds__(256) void rms_silu_k(
    const float* __restrict__ x, unsigned short* __restrict__ o,
    const float* __restrict__ w)
{
    const int row = blockIdx.x * 4 + ((int)threadIdx.x >> 6);
    const int lane = (int)threadIdx.x & 63;
    const float* xr = x + (size_t)row * 512;
    float4 v0 = *(const float4*)(xr + lane * 4);
    float4 v1 = *(const float4*)(xr + 256 + lane * 4);
    float q = v0.x*v0.x + v0.y*v0.y + v0.z*v0.z + v0.w*v0.w
            + v1.x*v1.x + v1.y*v1.y + v1.z*v1.z + v1.w*v1.w;
#pragma unroll
    for (int of = 32; of; of >>= 1) q += __shfl_xor(q, of, 64);
    const float scale = rsqrtf(q * (1.0f / 512.0f) + EPS);
    float4 w0 = *(const float4*)(w + lane * 4);
    float4 w1 = *(const float4*)(w + 256 + lane * 4);
    union { unsigned short u[4]; uint2 v; } p0, p1;
    p0.u[0] = f2bf(siluf_(v0.x * scale * w0.x));
    p0.u[1] = f2bf(siluf_(v0.y * scale * w0.y));
    p0.u[2] = f2bf(siluf_(v0.z * scale * w0.z));
    p0.u[3] = f2bf(siluf_(v0.w * scale * w0.w));
    p1.u[0] = f2bf(siluf_(v1.x * scale * w1.x));
    p1.u[1] = f2bf(siluf_(v1.y * scale * w1.y));
    p1.u[2] = f2bf(siluf_(v1.z * scale * w1.z));
    p1.u[3] = f2bf(siluf_(v1.w * scale * w1.w));
    unsigned short* ob = o + (size_t)row * 512;
    *(uint2*)(ob + lane * 4) = p0.v;
    *(uint2*)(ob + 256 + lane * 4) = p1.v;
}

// ---------------------------------------------------------------------------
__global__ __launch_bounds__(256) void conv_silu_k2(
    const unsigned short* __restrict__ xz, unsigned short* __restrict__ ub,
    const float* __restrict__ cw, const float* __restrict__ cb)
{
    int t = blockIdx.x * 256 + (int)threadIdx.x;
    int d = t & 1023;
    int bc = t >> 10;
    int b = bc >> 4, ch = bc & 15;
    int l0 = ch * 64;
    float4 w4 = *(const float4*)(cw + (size_t)d * 4);
    float bias = cb[d];
    const unsigned short* src = xz + ((size_t)(b * 1024 + l0)) * 2048 + d;
    unsigned short* dst = ub + ((size_t)(b * 1024 + l0)) * 1024 + d;
    float x0 = 0.f, x1 = 0.f, x2 = 0.f;
    if (l0 > 0) {
        x0 = bf2f(src[-(size_t)3 * 2048]);
        x1 = bf2f(src[-(size_t)2 * 2048]);
        x2 = bf2f(src[-(size_t)1 * 2048]);
    }
    for (int l = 0; l < 64; ++l) {
        float x3 = bf2f(src[(size_t)l * 2048]);
        float v = fmaf(x0, w4.x, fmaf(x1, w4.y, fmaf(x2, w4.z, fmaf(x3, w4.w, bias))));
        dst[(size_t)l * 1024] = f2bf(siluf_(v));
        x0 = x1; x1 = x2; x2 = x3;
    }
}

// ---------------------------------------------------------------------------
// Split-L scan v6: 8 chunks x 128 l, grid 1024. Conflict-free transposed
// LDS layout SDT[64 d][17 x float4] (stride 68). Reg-prefetch next sub-chunk.
// Thread = (dl 0..63, qq 0..3); per-wave staging of 4 l-pairs.
// ---------------------------------------------------------------------------
template <int CTRL>
DEV_INLINE float dpp_f(float x) {
    int yi = __builtin_amdgcn_update_dpp(
        0, __builtin_bit_cast(int, x), CTRL, 0xF, 0xF, true);
    return __builtin_bit_cast(float, yi);
}

template <int PHASE>
__global__ __launch_bounds__(256) void scan6(
    const unsigned short* __restrict__ dtp,
    const unsigned short* ubf,
    unsigned short* ybf,
    const unsigned short* __restrict__ xdbc,
    const unsigned short* __restrict__ zbf,
    float* __restrict__ hp,                  // per (b,d): 8 chunks x 16n {h,prod}
    const float* __restrict__ A_log,
    const float* __restrict__ Dp)
{
    __shared__ float SDT[64 * 68];           // [dl][l2*4]: {dt0,dtu0,dt1,dtu1}
    __shared__ float SB[32][20];
    __shared__ float SC[PHASE == 2 ? 32 : 1][20];
    __shared__ float YS[PHASE == 2 ? 32 : 1][68];

    const int lin = (int)blockIdx.x;
    const int logical = (lin & 7) * 128 + (lin >> 3);
    const int gg = logical & 15;
    const int r = logical >> 4;
    const int c = r & 7, b = r >> 3;
    if (PHASE == 1 && c == 7) return;
    const int tid = (int)threadIdx.x;
    const int dl = tid >> 2, qq = tid & 3;
    const int wv = tid >> 6;
    const int lane = tid & 63;
    const int dblk = gg << 6;
    const int d = dblk + dl;
    const int m0 = b * 1024 + c * 128;

    float An[4];
#pragma unroll
    for (int j = 0; j < 4; ++j)
        An[j] = -__expf(A_log[(size_t)d * 16 + qq * 4 + j]);

    float h[4] = {};
    float prod[4] = {1.f, 1.f, 1.f, 1.f};
    if (PHASE == 2) {
        const float* hpb = hp + ((size_t)(b * 1024 + d)) * 256 + qq * 8;
        for (int cc = 0; cc < c; ++cc) {
            float4 v0 = *(const float4*)(hpb + cc * 32);
            float4 v1 = *(const float4*)(hpb + cc * 32 + 4);
            h[0] = fmaf(v0.y, h[0], v0.x);
            h[1] = fmaf(v0.w, h[1], v0.z);
            h[2] = fmaf(v1.y, h[2], v1.x);
            h[3] = fmaf(v1.w, h[3], v1.z);
        }
    }

    // B/C staging role
    const int bcr = (tid & 127) >> 2;    // row 0..31
    const int bne = (tid & 3) << 2;      // n offset

    // prefetch registers
    unsigned short rdt0[4], rdt1[4], ru0[4], ru1[4];
    uint2 rBC;

    // ---- load sub-chunk 0 ----
#pragma unroll
    for (int j = 0; j < 4; ++j) {
        size_t r0 = (size_t)(m0 + 2 * (wv * 4 + j));
        rdt0[j] = dtp[r0 * 1024 + dblk + lane];
        rdt1[j] = dtp[(r0 + 1) * 1024 + dblk + lane];
        ru0[j]  = ubf[r0 * 1024 + dblk + lane];
        ru1[j]  = ubf[(r0 + 1) * 1024 + dblk + lane];
    }
    if (tid < 128) {
        rBC = *(const uint2*)(xdbc + (size_t)(m0 + bcr) * 64 + 32 + bne);
    } else if (PHASE == 2) {
        rBC = *(const uint2*)(xdbc + (size_t)(m0 + bcr) * 64 + 48 + bne);
    }

    for (int s = 0; s < 4; ++s) {
        const int lbase = s * 32;
        if (PHASE == 1 && s > 0) __syncthreads();   // p2 has sync after compute
        // ---- regs -> LDS ----
#pragma unroll
        for (int j = 0; j < 4; ++j) {
            float d0 = bf2f(rdt0[j]), d1 = bf2f(rdt1[j]);
            float4 wvv = {d0, d0 * bf2f(ru0[j]), d1, d1 * bf2f(ru1[j])};
            *(float4*)&SDT[lane * 68 + (wv * 4 + j) * 4] = wvv;
        }
        if (tid < 128) {
            const unsigned short* bb = (const unsigned short*)&rBC;
            float4 bv = {bf2f(bb[0]), bf2f(bb[1]), bf2f(bb[2]), bf2f(bb[3])};
            *(float4*)&SB[bcr][bne] = bv;
        } else if (PHASE == 2) {
            const unsigned short* cc2 = (const unsigned short*)&rBC;
            float4 cv = {bf2f(cc2[0]), bf2f(cc2[1]), bf2f(cc2[2]), bf2f(cc2[3])};
            *(float4*)&SC[bcr][bne] = cv;
        }
        // ---- issue next sub-chunk loads ----
        if (s < 3) {
            const int nb = lbase + 32;
#pragma unroll
            for (int j = 0; j < 4; ++j) {
                size_t r0 = (size_t)(m0 + nb + 2 * (wv * 4 + j));
                rdt0[j] = dtp[r0 * 1024 + dblk + lane];
                rdt1[j] = dtp[(r0 + 1) * 1024 + dblk + lane];
                ru0[j]  = ubf[r0 * 1024 + dblk + lane];
                ru1[j]  = ubf[(r0 + 1) * 1024 + dblk + lane];
            }
            if (tid < 128) {
                rBC = *(const uint2*)(xdbc + (size_t)(m0 + nb + bcr) * 64 + 32 + bne);
            } else if (PHASE == 2) {
                rBC = *(const uint2*)(xdbc + (size_t)(m0 + nb + bcr) * 64 + 48 + bne);
            }
        }
        __syncthreads();

        // ---- scan 32 steps (16 l-pairs) ----
        for (int l2 = 0; l2 < 16; ++l2) {
            float4 sd = *(const float4*)&SDT[dl * 68 + l2 * 4];
            float4 B0 = *(const float4*)&SB[2 * l2][qq * 4];
            float4 B1 = *(const float4*)&SB[2 * l2 + 1][qq * 4];
            float p0 = 0.0f, p1 = 0.0f;
            float4 C0, C1;
            if (PHASE == 2) {
                C0 = *(const float4*)&SC[2 * l2][qq * 4];
                C1 = *(const float4*)&SC[2 * l2 + 1][qq * 4];
            }
            const float* B0p = (const float*)&B0;
            const float* B1p = (const float*)&B1;
            const float* C0p = (const float*)&C0;
            const float* C1p = (const float*)&C1;
#pragma unroll
            for (int j = 0; j < 4; ++j) {
                float e0 = __expf(sd.x * An[j]);
                if (PHASE == 1) prod[j] *= e0;
                h[j] = fmaf(e0, h[j], sd.y * B0p[j]);
                if (PHASE == 2) p0 = fmaf(h[j], C0p[j], p0);
                float e1 = __expf(sd.z * An[j]);
                if (PHASE == 1) prod[j] *= e1;
                h[j] = fmaf(e1, h[j], sd.w * B1p[j]);
                if (PHASE == 2) p1 = fmaf(h[j], C1p[j], p1);
            }
            if (PHASE == 2) {
                p0 += dpp_f<0xB1>(p0);
                p0 += dpp_f<0x4E>(p0);
                p1 += dpp_f<0xB1>(p1);
                p1 += dpp_f<0x4E>(p1);
                if (qq == 0) {
                    YS[2 * l2][dl] = p0;
                    YS[2 * l2 + 1][dl] = p1;
                }
            }
        }

        // ---- store y = (p + u*D) * silu(z), bf16 ----
        if (PHASE == 2) {
            __syncthreads();
            const int row = tid >> 3;
            const int e8 = (tid & 7) * 8;
            size_t gr = (size_t)(m0 + lbase + row);
            float4 p40 = *(const float4*)&YS[row][e8];
            float4 p41 = *(const float4*)&YS[row][e8 + 4];
            uint4 uu = *(const uint4*)(ubf + gr * 1024 + dblk + e8);
            uint4 zz = *(const uint4*)(zbf + gr * 2048 + 1024 + dblk + e8);
            float4 D0 = *(const float4*)(Dp + dblk + e8);
            float4 D1 = *(const float4*)(Dp + dblk + e8 + 4);
            const unsigned short* up = (const unsigned short*)&uu;
            const unsigned short* zp = (const unsigned short*)&zz;
            const float* pp0 = (const float*)&p40;
            const float* pp1 = (const float*)&p41;
            const float* dd0 = (const float*)&D0;
            const float* dd1 = (const float*)&D1;
            union { unsigned short u[8]; uint4 v; } pk;
#pragma unroll
            for (int j = 0; j < 4; ++j) {
                float y = fmaf(bf2f(up[j]), dd0[j], pp0[j]) * siluf_(bf2f(zp[j]));
                pk.u[j] = f2bf(y);
            }
#pragma unroll
            for (int j = 0; j < 4; ++j) {
                float y = fmaf(bf2f(up[4 + j]), dd1[j], pp1[j]) * siluf_(bf2f(zp[4 + j]));
                pk.u[4 + j] = f2bf(y);
            }
            __syncthreads();   // YS reads done before next iter's compute writes
            *(uint4*)(ybf + gr * 1024 + dblk + e8) = pk.v;
        }
    }

    if (PHASE == 1) {
        float* hpo = hp + ((size_t)(b * 1024 + d)) * 256 + c * 32 + qq * 8;
        float4 o0 = {h[0], prod[0], h[1], prod[1]};
        float4 o1 = {h[2], prod[2], h[3], prod[3]};
        *(float4*)hpo = o0;
        *(float4*)(hpo + 4) = o1;
    }
}

// ---------------------------------------------------------------------------
extern "C" void kernel_launch(void* const* d_in, const int* in_sizes, int n_in,
                              void* d_out, int out_size, void* d_ws, size_t ws_size,
                              hipStream_t stream)
{
    const float* motion     = (const float*)d_in[0];
    const float* skip       = (const float*)d_in[1];
    const float* embed      = (const float*)d_in[2];
    const float* w_up       = (const float*)d_in[3];
    const float* b_up       = (const float*)d_in[4];
    const float* w1         = (const float*)d_in[5];
    const float* b1         = (const float*)d_in[6];
    const float* rms_w      = (const float*)d_in[7];
    const float* w2         = (const float*)d_in[8];
    const float* b2         = (const float*)d_in[9];
    const float* ln_w       = (const float*)d_in[10];
    const float* ln_b       = (const float*)d_in[11];
    const float* in_proj_w  = (const float*)d_in[12];
    const float* conv_w     = (const float*)d_in[13];
    const float* conv_b     = (const float*)d_in[14];
    const float* x_proj_w   = (const float*)d_in[15];
    const float* dt_proj_w  = (const float*)d_in[16];
    const float* dt_proj_b  = (const float*)d_in[17];
    const float* A_log      = (const float*)d_in[18];
    const float* D_param    = (const float*)d_in[19];
    const float* out_proj_w = (const float*)d_in[20];
    const float* out_proj_b = (const float*)d_in[21];
    const float* norm_f_w   = (const float*)d_in[22];
    const float* norm_f_b   = (const float*)d_in[23];
    float* out = (float*)d_out;
    float* ws = (float*)d_ws;

    float* xbuf = ws;                                        // (8192x512) f32
    float* xlnf = ws + 4194304;                              // (8192x512) f32
    unsigned short* xzbf  = (unsigned short*)(ws + 8388608); // (8192x2048) bf16
    unsigned short* ubf   = (unsigned short*)(ws + 16777216);// (8192x1024) bf16
    unsigned short* dtybf = (unsigned short*)(ws + 20971520);// (8192x1024) bf16
    unsigned short* xdbc  = (unsigned short*)(ws + 25165824);// (8192x64) bf16
    float* hp  = ws + 25427968;                              // 2M f
    unsigned short* xsbf = (unsigned short*)(ws + 29622272); // (8192x512) bf16
    unsigned short* mbf  = (unsigned short*)(ws + 31719424); // 2M bf16
    unsigned short* wupT = (unsigned short*)(ws + 32768000); // 512K bf16
    unsigned short* w1b  = (unsigned short*)(ws + 33030144); // 512K bf16
    unsigned short* w2b  = (unsigned short*)(ws + 33292288); // 256K bf16
    unsigned short* lw   = (unsigned short*)(ws + 33423360); // 4 x 1671168 bf16

    unsigned short* x0bf = xzbf;

    dim3 blk(256);

    prep_all<<<dim3(5696), blk, 0, stream>>>(
        motion, w_up, w1, w2, in_proj_w, out_proj_w, x_proj_w, dt_proj_w,
        mbf, wupT, w1b, w2b, lw);

    gemm_mfma64<0, false, false, true, true><<<dim3(1024), blk, 0, stream>>>(
        mbf, 512, wupT, 512, x0bf, 0, 1024, 512, 16, b_up, nullptr);
    concat_skip<<<dim3(2048), blk, 0, stream>>>(skip, x0bf);

    gemm_mfma64<0, false, false, false, false><<<dim3(1024), blk, 0, stream>>>(
        x0bf, 1024, w1b, 1024, xlnf, 512, 512, 1024, 8, b1, nullptr);
    rms_silu_k<<<dim3(2048), blk, 0, stream>>>(xlnf, xsbf, rms_w);

    gemm_mfma64<0, false, true, false, false><<<dim3(1024), blk, 0, stream>>>(
        xsbf, 512, w2b, 512, xbuf, 512, 512, 512, 8, b2, embed);

    for (int i = 0; i < 4; ++i) {
        unsigned short* ipw = lw + (size_t)i * 1671168;
        unsigned short* opw = ipw + 1048576;
        unsigned short* xpw = ipw + 1572864;
        unsigned short* wdt = ipw + 1638400;
        layernorm_k<true><<<dim3(2048), blk, 0, stream>>>(
            xbuf, xsbf, ln_w + (size_t)i * 512, ln_b + (size_t)i * 512);
        gemm_mfma<0, false, false, true><<<dim3(1024), blk, 0, stream>>>(
            xsbf, 512, ipw, 512, xzbf, 2048, 2048, 512, 16, nullptr, nullptr);
        conv_silu_k2<<<dim3(512), blk, 0, stream>>>(
            xzbf, ubf, conv_w + (size_t)i * 4096, conv_b + (size_t)i * 1024);
        gemm_xdbc<<<dim3(128), dim3(128), 0, stream>>>(ubf, xpw, xdbc);
        gemm_dt<<<dim3(512), blk, 0, stream>>>(
            xdbc, wdt, dt_proj_b + (size_t)i * 1024, dtybf);
        scan6<1><<<dim3(1024), blk, 0, stream>>>(
            dtybf, ubf, nullptr, xdbc, xzbf, hp,
            A_log + (size_t)i * 16384, D_param + (size_t)i * 1024);
        scan6<2><<<dim3(1024), blk, 0, stream>>>(
            dtybf, ubf, ubf, xdbc, xzbf, hp,
            A_log + (size_t)i * 16384, D_param + (size_t)i * 1024);
        gemm_mfma64<0, true, false, false, false><<<dim3(1024), blk, 0, stream>>>(
            ubf, 1024, opw, 1024, xbuf, 512, 512, 1024, 8,
            out_proj_b + (size_t)i * 512, nullptr);
    }

    layernorm_k<false><<<dim3(2048), blk, 0, stream>>>(xbuf, out, norm_f_w, norm_f_b);
}

// Round 10
// 694.734 us; speedup vs baseline: 1.0056x; 1.0056x over previous
//
#include <hip/hip_runtime.h>
#include <cstdint>
#include <cstddef>

#define DEV_INLINE __device__ __forceinline__

static constexpr float EPS = 1e-5f;

DEV_INLINE float sigmoidf_(float x) { return 1.0f / (1.0f + __expf(-x)); }
DEV_INLINE float siluf_(float x) { return x * sigmoidf_(x); }
DEV_INLINE float softplus_fast(float x) {
    return fmaxf(x, 0.0f) + __logf(1.0f + __expf(-fabsf(x)));
}
DEV_INLINE unsigned short f2bf(float x) {   // RNE f32 -> bf16
    unsigned u = __builtin_bit_cast(unsigned, x);
    u += 0x7FFFu + ((u >> 16) & 1u);
    return (unsigned short)(u >> 16);
}
DEV_INLINE float bf2f(unsigned short s) {
    unsigned u = ((unsigned)s) << 16;
    return __builtin_bit_cast(float, u);
}

typedef __attribute__((ext_vector_type(8))) short bf16x8;
typedef __attribute__((ext_vector_type(4))) float f32x4;

DEV_INLINE void gload16(const unsigned short* src, char* ldsdst) {
    __builtin_amdgcn_global_load_lds(
        (const __attribute__((address_space(1))) unsigned int*)src,
        (__attribute__((address_space(3))) unsigned int*)ldsdst, 16, 0, 0);
}

DEV_INLINE void cvt8(const float* __restrict__ s, unsigned short* __restrict__ d, int t) {
    float4 f0 = *(const float4*)(s + (size_t)t * 8);
    float4 f1 = *(const float4*)(s + (size_t)t * 8 + 4);
    union { unsigned short u[8]; uint4 v; } pk;
    pk.u[0] = f2bf(f0.x); pk.u[1] = f2bf(f0.y); pk.u[2] = f2bf(f0.z); pk.u[3] = f2bf(f0.w);
    pk.u[4] = f2bf(f1.x); pk.u[5] = f2bf(f1.y); pk.u[6] = f2bf(f1.z); pk.u[7] = f2bf(f1.w);
    *(uint4*)(d + (size_t)t * 8) = pk.v;
}

// ---------------------------------------------------------------------------
// One-shot prep: motion cvt | w_up transpose | w1 | w2 | 4x layer weights.
// ---------------------------------------------------------------------------
__global__ __launch_bounds__(256) void prep_all(
    const float* __restrict__ motion, const float* __restrict__ wup,
    const float* __restrict__ w1, const float* __restrict__ w2,
    const float* __restrict__ in_proj_w, const float* __restrict__ out_proj_w,
    const float* __restrict__ x_proj_w, const float* __restrict__ dt_proj_w,
    unsigned short* __restrict__ mbf, unsigned short* __restrict__ wupT,
    unsigned short* __restrict__ w1b, unsigned short* __restrict__ w2b,
    unsigned short* __restrict__ lw)
{
    int bid = (int)blockIdx.x, tid = (int)threadIdx.x;
    if (bid < 1024) {
        cvt8(motion, mbf, bid * 256 + tid);
    } else if (bid < 2048) {
        int t = (bid - 1024) * 256 + tid;
        int c = t >> 9, o = t & 511;
        float2 v = *(const float2*)(wup + (size_t)t * 2);
        wupT[(size_t)o * 512 + c] = f2bf(v.x);
        wupT[262144 + (size_t)o * 512 + c] = f2bf(v.y);
    } else if (bid < 2304) {
        cvt8(w1, w1b, (bid - 2048) * 256 + tid);
    } else if (bid < 2432) {
        cvt8(w2, w2b, (bid - 2304) * 256 + tid);
    } else {
        int r = bid - 2432;
        int layer = r / 816;
        int lb = r - layer * 816;
        unsigned short* base = lw + (size_t)layer * 1671168;
        if (lb < 512) {
            cvt8(in_proj_w + (size_t)layer * 1048576, base, lb * 256 + tid);
        } else if (lb < 768) {
            cvt8(out_proj_w + (size_t)layer * 524288, base + 1048576,
                 (lb - 512) * 256 + tid);
        } else if (lb < 800) {
            cvt8(x_proj_w + (size_t)layer * 65536, base + 1572864,
                 (lb - 768) * 256 + tid);
        } else {
            cvt8(dt_proj_w + (size_t)layer * 32768, base + 1638400,
                 (lb - 800) * 256 + tid);
        }
    }
}

// ---------------------------------------------------------------------------
// MFMA GEMM 128x128
// ---------------------------------------------------------------------------
template <int ACT, bool ACC, bool EMBED, bool OBF>
__global__ __launch_bounds__(256) void gemm_mfma(
    const unsigned short* __restrict__ A, int lda,
    const unsigned short* __restrict__ W, int ldw,
    void* __restrict__ Cv, int ldc, int N, int K, int gx,
    const float* __restrict__ bias, const float* __restrict__ embed)
{
    __shared__ unsigned short Asm[2][128 * 64];
    __shared__ unsigned short Wsm[2][128 * 64];
    const int tid = (int)threadIdx.x;
    const int lane = tid & 63;
    const int wv = tid >> 6;
    const int wm = wv >> 1, wn = wv & 1;

    const int nwg = (int)gridDim.x;
    const int lin = (int)blockIdx.x;
    const int logical = (lin & 7) * (nwg >> 3) + (lin >> 3);
    const int by = logical / gx;
    const int bx = logical - by * gx;
    const int bm = by * 128, bn = bx * 128;

    f32x4 acc[4][4] = {};
    const int l8 = lane >> 3;
    const int wc = lane & 7;
    const int wcg = wc ^ l8;
    const int NT = K >> 6;

    {
        char* aB = (char*)Asm[0];
        char* bB = (char*)Wsm[0];
#pragma unroll
        for (int i = 0; i < 4; ++i) {
            int rb = (i * 4 + wv) * 8;
            gload16(W + (size_t)(bn + rb + l8) * ldw + wcg * 8, bB + rb * 128);
            gload16(A + (size_t)(bm + rb + l8) * lda + wcg * 8, aB + rb * 128);
        }
    }
    __syncthreads();

    for (int t = 0; t < NT; ++t) {
        const int cur = t & 1;
        if (t + 1 < NT) {
            const int k1 = (t + 1) << 6;
            char* aB = (char*)Asm[cur ^ 1];
            char* bB = (char*)Wsm[cur ^ 1];
#pragma unroll
            for (int i = 0; i < 4; ++i) {
                int rb = (i * 4 + wv) * 8;
                gload16(W + (size_t)(bn + rb + l8) * ldw + k1 + wcg * 8, bB + rb * 128);
                gload16(A + (size_t)(bm + rb + l8) * lda + k1 + wcg * 8, aB + rb * 128);
            }
        }
        const char* aB = (const char*)Asm[cur];
        const char* bB = (const char*)Wsm[cur];
        const int rA = wm * 64 + (lane & 15);
        const int rB = wn * 64 + (lane & 15);
        const int q = lane >> 4;
#pragma unroll
        for (int kk = 0; kk < 2; ++kk) {
            bf16x8 af[4], bfr[4];
#pragma unroll
            for (int mi = 0; mi < 4; ++mi) {
                int row = rA + mi * 16;
                int ch = (kk * 4 + q) ^ (row & 7);
                af[mi] = *(const bf16x8*)(aB + row * 128 + ch * 16);
            }
#pragma unroll
            for (int ni = 0; ni < 4; ++ni) {
                int row = rB + ni * 16;
                int ch = (kk * 4 + q) ^ (row & 7);
                bfr[ni] = *(const bf16x8*)(bB + row * 128 + ch * 16);
            }
#pragma unroll
            for (int mi = 0; mi < 4; ++mi)
#pragma unroll
                for (int ni = 0; ni < 4; ++ni)
                    acc[mi][ni] = __builtin_amdgcn_mfma_f32_16x16x32_bf16(
                        af[mi], bfr[ni], acc[mi][ni], 0, 0, 0);
        }
        __syncthreads();
    }

    const int cn = lane & 15;
    const int r0 = (lane >> 4) * 4;
    const int eb = EMBED ? (bm >> 10) * N : 0;
#pragma unroll
    for (int ni = 0; ni < 4; ++ni) {
        int col = bn + wn * 64 + ni * 16 + cn;
        float add = bias ? bias[col] : 0.0f;
        if (EMBED) add += embed[eb + col];
#pragma unroll
        for (int mi = 0; mi < 4; ++mi) {
#pragma unroll
            for (int r = 0; r < 4; ++r) {
                int row = bm + wm * 64 + mi * 16 + r0 + r;
                float v = acc[mi][ni][r] + add;
                if (ACT == 1) v = softplus_fast(v);
                if (OBF) {
                    ((unsigned short*)Cv)[(size_t)row * ldc + col] = f2bf(v);
                } else {
                    float* p = (float*)Cv + (size_t)row * ldc + col;
                    if (ACC) *p += v; else *p = v;
                }
            }
        }
    }
}

// ---------------------------------------------------------------------------
// MFMA GEMM 64x64. UPS: upsample epilogue.
// ---------------------------------------------------------------------------
template <int ACT, bool ACC, bool EMBED, bool OBF, bool UPS>
__global__ __launch_bounds__(256) void gemm_mfma64(
    const unsigned short* __restrict__ A, int lda,
    const unsigned short* __restrict__ W, int ldw,
    void* __restrict__ Cv, int ldc, int N, int K, int gx,
    const float* __restrict__ bias, const float* __restrict__ embed)
{
    __shared__ unsigned short Asm[2][64 * 64];
    __shared__ unsigned short Wsm[2][64 * 64];
    const int tid = (int)threadIdx.x;
    const int lane = tid & 63;
    const int wv = tid >> 6;
    const int wm = wv >> 1, wn = wv & 1;

    const int nwg = (int)gridDim.x;
    const int lin = (int)blockIdx.x;
    const int logical = (lin & 7) * (nwg >> 3) + (lin >> 3);
    const int by = logical / gx;
    const int bx = logical - by * gx;
    const int bm = by * 64, bn = bx * 64;

    f32x4 acc[2][2] = {};
    const int l8 = lane >> 3;
    const int wc = lane & 7;
    const int wcg = wc ^ l8;
    const int NT = K >> 6;

    {
        char* aB = (char*)Asm[0];
        char* bB = (char*)Wsm[0];
#pragma unroll
        for (int i = 0; i < 2; ++i) {
            int rb = (i * 4 + wv) * 8;
            gload16(W + (size_t)(bn + rb + l8) * ldw + wcg * 8, bB + rb * 128);
            gload16(A + (size_t)(bm + rb + l8) * lda + wcg * 8, aB + rb * 128);
        }
    }
    __syncthreads();

    for (int t = 0; t < NT; ++t) {
        const int cur = t & 1;
        if (t + 1 < NT) {
            const int k1 = (t + 1) << 6;
            char* aB = (char*)Asm[cur ^ 1];
            char* bB = (char*)Wsm[cur ^ 1];
#pragma unroll
            for (int i = 0; i < 2; ++i) {
                int rb = (i * 4 + wv) * 8;
                gload16(W + (size_t)(bn + rb + l8) * ldw + k1 + wcg * 8, bB + rb * 128);
                gload16(A + (size_t)(bm + rb + l8) * lda + k1 + wcg * 8, aB + rb * 128);
            }
        }
        const char* aB = (const char*)Asm[cur];
        const char* bB = (const char*)Wsm[cur];
        const int rA = wm * 32 + (lane & 15);
        const int rB = wn * 32 + (lane & 15);
        const int q = lane >> 4;
#pragma unroll
        for (int kk = 0; kk < 2; ++kk) {
            bf16x8 af[2], bfr[2];
#pragma unroll
            for (int mi = 0; mi < 2; ++mi) {
                int row = rA + mi * 16;
                int ch = (kk * 4 + q) ^ (row & 7);
                af[mi] = *(const bf16x8*)(aB + row * 128 + ch * 16);
            }
#pragma unroll
            for (int ni = 0; ni < 2; ++ni) {
                int row = rB + ni * 16;
                int ch = (kk * 4 + q) ^ (row & 7);
                bfr[ni] = *(const bf16x8*)(bB + row * 128 + ch * 16);
            }
#pragma unroll
            for (int mi = 0; mi < 2; ++mi)
#pragma unroll
                for (int ni = 0; ni < 2; ++ni)
                    acc[mi][ni] = __builtin_amdgcn_mfma_f32_16x16x32_bf16(
                        af[mi], bfr[ni], acc[mi][ni], 0, 0, 0);
        }
        __syncthreads();
    }

    const int cn = lane & 15;
    const int r0 = (lane >> 4) * 4;
    const int eb = EMBED ? (bm >> 10) * N : 0;
#pragma unroll
    for (int ni = 0; ni < 2; ++ni) {
        int col = bn + wn * 32 + ni * 16 + cn;
        float add = bias ? bias[UPS ? (col & 511) : col] : 0.0f;
        if (EMBED) add += embed[eb + col];
#pragma unroll
        for (int mi = 0; mi < 2; ++mi) {
#pragma unroll
            for (int r = 0; r < 4; ++r) {
                int row = bm + wm * 32 + mi * 16 + r0 + r;
                float v = acc[mi][ni][r] + add;
                if (ACT == 1) v = softplus_fast(v);
                if (UPS) {
                    size_t ad = (size_t)row * 2048 + ((col >> 9) << 10) + (col & 511);
                    ((unsigned short*)Cv)[ad] = f2bf(v);
                } else if (OBF) {
                    ((unsigned short*)Cv)[(size_t)row * ldc + col] = f2bf(v);
                } else {
                    float* p = (float*)Cv + (size_t)row * ldc + col;
                    if (ACC) *p += v; else *p = v;
                }
            }
        }
    }
}

// ---------------------------------------------------------------------------
// dt GEMM: dt[8192,1024] = softplus(dtp[8192,32] @ dtw[1024,32]^T + bias)
// ---------------------------------------------------------------------------
__global__ __launch_bounds__(256) void gemm_dt(
    const unsigned short* __restrict__ xdbc,
    const unsigned short* __restrict__ wdt,
    const float* __restrict__ bias,
    unsigned short* __restrict__ out)
{
    __shared__ unsigned short S[128 * 136];
    const int tid = (int)threadIdx.x;
    const int lane = tid & 63;
    const int wv = tid >> 6;
    const int wm = wv >> 1, wn = wv & 1;

    const int lin = (int)blockIdx.x;
    const int logical = (lin & 7) * 64 + (lin >> 3);
    const int bm = (logical >> 3) * 128;
    const int bn = (logical & 7) * 128;

    const int fr = lane & 15;
    const int q = lane >> 4;

    bf16x8 af[4], wf[4];
#pragma unroll
    for (int mi = 0; mi < 4; ++mi)
        af[mi] = *(const bf16x8*)(xdbc + (size_t)(bm + wm * 64 + mi * 16 + fr) * 64 + q * 8);
#pragma unroll
    for (int ni = 0; ni < 4; ++ni)
        wf[ni] = *(const bf16x8*)(wdt + (size_t)(bn + wn * 64 + ni * 16 + fr) * 32 + q * 8);

    f32x4 acc[4][4] = {};
#pragma unroll
    for (int mi = 0; mi < 4; ++mi)
#pragma unroll
        for (int ni = 0; ni < 4; ++ni)
            acc[mi][ni] = __builtin_amdgcn_mfma_f32_16x16x32_bf16(
                af[mi], wf[ni], acc[mi][ni], 0, 0, 0);

    const int cn = lane & 15;
    const int r0 = (lane >> 4) * 4;
#pragma unroll
    for (int ni = 0; ni < 4; ++ni) {
        int lcol = wn * 64 + ni * 16 + cn;
        float add = bias[bn + lcol];
#pragma unroll
        for (int mi = 0; mi < 4; ++mi) {
#pragma unroll
            for (int r = 0; r < 4; ++r) {
                int lrow = wm * 64 + mi * 16 + r0 + r;
                S[lrow * 136 + lcol] = f2bf(softplus_fast(acc[mi][ni][r] + add));
            }
        }
    }
    __syncthreads();

    const int row = tid >> 1;
    const int half = tid & 1;
    const unsigned short* src = S + row * 136 + half * 64;
    unsigned short* dst = out + (size_t)(bm + row) * 1024 + bn + half * 64;
#pragma unroll
    for (int k = 0; k < 8; ++k) {
        uint4 v = *(const uint4*)(src + k * 8);
        *(uint4*)(dst + k * 8) = v;
    }
}

// ---------------------------------------------------------------------------
// Skinny MFMA GEMM: xdbc[M,64] = u[M,1024] * xpw[64,1024]^T (bf16 out)
// ---------------------------------------------------------------------------
__global__ __launch_bounds__(128) void gemm_xdbc(
    const unsigned short* __restrict__ A,
    const unsigned short* __restrict__ W,
    unsigned short* __restrict__ C)
{
    __shared__ unsigned short Asm[64 * 64];
    __shared__ unsigned short Wsm[64 * 64];
    const int tid = (int)threadIdx.x;
    const int lane = tid & 63;
    const int w = tid >> 6;
    const int bm = blockIdx.x * 64;
    const int l8 = lane >> 3, wc = lane & 7, wcg = wc ^ l8;
    char* aB = (char*)Asm;
    char* bB = (char*)Wsm;

    f32x4 acc[2][4] = {};

    for (int k0 = 0; k0 < 1024; k0 += 64) {
#pragma unroll
        for (int i = 0; i < 4; ++i) {
            int rb = (i * 2 + w) * 8;
            gload16(A + (size_t)(bm + rb + l8) * 1024 + k0 + wcg * 8, aB + rb * 128);
            gload16(W + (size_t)(rb + l8) * 1024 + k0 + wcg * 8, bB + rb * 128);
        }
        __syncthreads();
        const int rA = w * 32 + (lane & 15);
        const int rB = (lane & 15);
        const int q = lane >> 4;
#pragma unroll
        for (int kk = 0; kk < 2; ++kk) {
            bf16x8 af[2], bfr[4];
#pragma unroll
            for (int mi = 0; mi < 2; ++mi) {
                int row = rA + mi * 16;
                int ch = (kk * 4 + q) ^ (row & 7);
                af[mi] = *(const bf16x8*)(aB + row * 128 + ch * 16);
            }
#pragma unroll
            for (int ni = 0; ni < 4; ++ni) {
                int row = rB + ni * 16;
                int ch = (kk * 4 + q) ^ (row & 7);
                bfr[ni] = *(const bf16x8*)(bB + row * 128 + ch * 16);
            }
#pragma unroll
            for (int mi = 0; mi < 2; ++mi)
#pragma unroll
                for (int ni = 0; ni < 4; ++ni)
                    acc[mi][ni] = __builtin_amdgcn_mfma_f32_16x16x32_bf16(
                        af[mi], bfr[ni], acc[mi][ni], 0, 0, 0);
        }
        __syncthreads();
    }
    const int cn = lane & 15;
    const int r0 = (lane >> 4) * 4;
#pragma unroll
    for (int mi = 0; mi < 2; ++mi)
#pragma unroll
        for (int ni = 0; ni < 4; ++ni)
#pragma unroll
            for (int r = 0; r < 4; ++r) {
                int row = bm + w * 32 + mi * 16 + r0 + r;
                C[(size_t)row * 64 + ni * 16 + cn] = f2bf(acc[mi][ni][r]);
            }
}

// ---------------------------------------------------------------------------
__global__ __launch_bounds__(256) void concat_skip(
    const float* __restrict__ skip, unsigned short* __restrict__ x0)
{
    int t = blockIdx.x * 256 + (int)threadIdx.x;
    int row = t >> 6;
    int c8 = (t & 63) << 3;
    const float* s = skip + (size_t)row * 512 + c8;
    float4 f0 = *(const float4*)s;
    float4 f1 = *(const float4*)(s + 4);
    union { unsigned short u[8]; uint4 v; } pk;
    pk.u[0] = f2bf(f0.x); pk.u[1] = f2bf(f0.y); pk.u[2] = f2bf(f0.z); pk.u[3] = f2bf(f0.w);
    pk.u[4] = f2bf(f1.x); pk.u[5] = f2bf(f1.y); pk.u[6] = f2bf(f1.z); pk.u[7] = f2bf(f1.w);
    *(uint4*)(x0 + (size_t)row * 1024 + 512 + c8) = pk.v;
}

// ---------------------------------------------------------------------------
template <bool BFOUT>
__global__ __launch_bounds__(256) void layernorm_k(
    const float* __restrict__ x, void* __restrict__ outp,
    const float* __restrict__ w, const float* __restrict__ b)
{
    const int row = blockIdx.x * 4 + ((int)threadIdx.x >> 6);
    const int lane = (int)threadIdx.x & 63;
    const float* xr = x + (size_t)row * 512;
    float4 v0 = *(const float4*)(xr + lane * 4);
    float4 v1 = *(const float4*)(xr + 256 + lane * 4);
    float s = v0.x + v0.y + v0.z + v0.w + v1.x + v1.y + v1.z + v1.w;
    float q = v0.x*v0.x + v0.y*v0.y + v0.z*v0.z + v0.w*v0.w
            + v1.x*v1.x + v1.y*v1.y + v1.z*v1.z + v1.w*v1.w;
#pragma unroll
    for (int o = 32; o; o >>= 1) {
        s += __shfl_xor(s, o, 64);
        q += __shfl_xor(q, o, 64);
    }
    const float mean = s * (1.0f / 512.0f);
    const float var = q * (1.0f / 512.0f) - mean * mean;
    const float rstd = rsqrtf(var + EPS);
    float4 w0 = *(const float4*)(w + lane * 4);
    float4 w1 = *(const float4*)(w + 256 + lane * 4);
    float4 b0 = *(const float4*)(b + lane * 4);
    float4 b1 = *(const float4*)(b + 256 + lane * 4);
    float4 o0, o1;
    o0.x = (v0.x - mean) * rstd * w0.x + b0.x;
    o0.y = (v0.y - mean) * rstd * w0.y + b0.y;
    o0.z = (v0.z - mean) * rstd * w0.z + b0.z;
    o0.w = (v0.w - mean) * rstd * w0.w + b0.w;
    o1.x = (v1.x - mean) * rstd * w1.x + b1.x;
    o1.y = (v1.y - mean) * rstd * w1.y + b1.y;
    o1.z = (v1.z - mean) * rstd * w1.z + b1.z;
    o1.w = (v1.w - mean) * rstd * w1.w + b1.w;
    if (BFOUT) {
        unsigned short* ob = (unsigned short*)outp + (size_t)row * 512;
        union { unsigned short u[4]; uint2 v; } p0, p1;
        p0.u[0] = f2bf(o0.x); p0.u[1] = f2bf(o0.y); p0.u[2] = f2bf(o0.z); p0.u[3] = f2bf(o0.w);
        p1.u[0] = f2bf(o1.x); p1.u[1] = f2bf(o1.y); p1.u[2] = f2bf(o1.z); p1.u[3] = f2bf(o1.w);
        *(uint2*)(ob + lane * 4) = p0.v;
        *(uint2*)(ob + 256 + lane * 4) = p1.v;
    } else {
        float* orow = (float*)outp + (size_t)row * 512;
        *(float4*)(orow + lane * 4) = o0;
        *(float4*)(orow + 256 + lane * 4) = o1;
    }
}

__global__ __launch_bounds__(256) void rms_silu_k(
    const float* __restrict__ x, unsigned short* __restrict__ o,
    const float* __restrict__ w)
{
    const int row = blockIdx.x * 4 + ((int)threadIdx.x >> 6);
    const int lane = (int)threadIdx.x & 63;
    const float* xr = x + (size_t)row * 512;
    float4 v0 = *(const float4*)(xr + lane * 4);
    float4 v1 = *(const float4*)(xr + 256 + lane * 4);
    float q = v0.x*v0.x + v0.y*v0.y + v0.z*v0.z + v0.w*v0.w
            + v1.x*v1.x + v1.y*v1.y + v1.z*v1.z + v1.w*v1.w;
#pragma unroll
    for (int of = 32; of; of >>= 1) q += __shfl_xor(q, of, 64);
    const float scale = rsqrtf(q * (1.0f / 512.0f) + EPS);
    float4 w0 = *(const float4*)(w + lane * 4);
    float4 w1 = *(const float4*)(w + 256 + lane * 4);
    union { unsigned short u[4]; uint2 v; } p0, p1;
    p0.u[0] = f2bf(siluf_(v0.x * scale * w0.x));
    p0.u[1] = f2bf(siluf_(v0.y * scale * w0.y));
    p0.u[2] = f2bf(siluf_(v0.z * scale * w0.z));
    p0.u[3] = f2bf(siluf_(v0.w * scale * w0.w));
    p1.u[0] = f2bf(siluf_(v1.x * scale * w1.x));
    p1.u[1] = f2bf(siluf_(v1.y * scale * w1.y));
    p1.u[2] = f2bf(siluf_(v1.z * scale * w1.z));
    p1.u[3] = f2bf(siluf_(v1.w * scale * w1.w));
    unsigned short* ob = o + (size_t)row * 512;
    *(uint2*)(ob + lane * 4) = p0.v;
    *(uint2*)(ob + 256 + lane * 4) = p1.v;
}

// ---------------------------------------------------------------------------
__global__ __launch_bounds__(256) void conv_silu_k2(
    const unsigned short* __restrict__ xz, unsigned short* __restrict__ ub,
    const float* __restrict__ cw, const float* __restrict__ cb)
{
    int t = blockIdx.x * 256 + (int)threadIdx.x;
    int d = t & 1023;
    int bc = t >> 10;
    int b = bc >> 4, ch = bc & 15;
    int l0 = ch * 64;
    float4 w4 = *(const float4*)(cw + (size_t)d * 4);
    float bias = cb[d];
    const unsigned short* src = xz + ((size_t)(b * 1024 + l0)) * 2048 + d;
    unsigned short* dst = ub + ((size_t)(b * 1024 + l0)) * 1024 + d;
    float x0 = 0.f, x1 = 0.f, x2 = 0.f;
    if (l0 > 0) {
        x0 = bf2f(src[-(size_t)3 * 2048]);
        x1 = bf2f(src[-(size_t)2 * 2048]);
        x2 = bf2f(src[-(size_t)1 * 2048]);
    }
    for (int l = 0; l < 64; ++l) {
        float x3 = bf2f(src[(size_t)l * 2048]);
        float v = fmaf(x0, w4.x, fmaf(x1, w4.y, fmaf(x2, w4.z, fmaf(x3, w4.w, bias))));
        dst[(size_t)l * 1024] = f2bf(siluf_(v));
        x0 = x1; x1 = x2; x2 = x3;
    }
}

// ---------------------------------------------------------------------------
// Split-L scan v7: 8 chunks x 128 l, 128-thread blocks, 32 d per block,
// grid 2048 -> 8 blocks/CU (~16 waves/CU). Conflict-free SDT (stride 70),
// reg-prefetch next sub-chunk (T14). Thread = (dl 0..31, qq 0..3).
// ---------------------------------------------------------------------------
template <int CTRL>
DEV_INLINE float dpp_f(float x) {
    int yi = __builtin_amdgcn_update_dpp(
        0, __builtin_bit_cast(int, x), CTRL, 0xF, 0xF, true);
    return __builtin_bit_cast(float, yi);
}

template <int PHASE>
__global__ __launch_bounds__(128) void scan7(
    const unsigned short* __restrict__ dtp,
    const unsigned short* ubf,
    unsigned short* ybf,
    const unsigned short* __restrict__ xdbc,
    const unsigned short* __restrict__ zbf,
    float* __restrict__ hp,                  // per (b,d): 8 chunks x 16n {h,prod}
    const float* __restrict__ A_log,
    const float* __restrict__ Dp)
{
    __shared__ float SDT[32 * 70];           // [dl][l2*4 + half*2]: {dt, dtu}
    __shared__ float SB[32][20];
    __shared__ float SC[PHASE == 2 ? 32 : 1][20];
    __shared__ float YS[PHASE == 2 ? 32 : 1][36];

    const int lin = (int)blockIdx.x;
    const int logical = (lin & 7) * 256 + (lin >> 3);   // grid 2048, %8==0
    const int g = logical & 31;              // 32 d-groups
    const int r = logical >> 5;
    const int c = r & 7, b = r >> 3;
    if (PHASE == 1 && c == 7) return;
    const int tid = (int)threadIdx.x;
    const int dl = tid >> 2, qq = tid & 3;   // dl 0..31
    const int dblk = g << 5;
    const int d = dblk + dl;
    const int m0 = b * 1024 + c * 128;

    float An[4];
#pragma unroll
    for (int j = 0; j < 4; ++j)
        An[j] = -__expf(A_log[(size_t)d * 16 + qq * 4 + j]);

    float h[4] = {};
    float prod[4] = {1.f, 1.f, 1.f, 1.f};
    if (PHASE == 2) {
        const float* hpb = hp + ((size_t)(b * 1024 + d)) * 256 + qq * 8;
        for (int cc = 0; cc < c; ++cc) {
            float4 v0 = *(const float4*)(hpb + cc * 32);
            float4 v1 = *(const float4*)(hpb + cc * 32 + 4);
            h[0] = fmaf(v0.y, h[0], v0.x);
            h[1] = fmaf(v0.w, h[1], v0.z);
            h[2] = fmaf(v1.y, h[2], v1.x);
            h[3] = fmaf(v1.w, h[3], v1.z);
        }
    }

    // staging roles
    const int sr = tid >> 3;             // rows sr and 16+sr
    const int sg = (tid & 7) * 4;        // 4 d's
    const int bcr = tid >> 2;            // B/C row 0..31
    const int bne = (tid & 3) << 2;      // n offset

    uint2 rd0, rd1, ru0, ru1, rB, rC;

    {   // ---- load sub-chunk 0 ----
        size_t ra = (size_t)(m0 + sr);
        size_t rb2 = (size_t)(m0 + 16 + sr);
        rd0 = *(const uint2*)(dtp + ra * 1024 + dblk + sg);
        rd1 = *(const uint2*)(dtp + rb2 * 1024 + dblk + sg);
        ru0 = *(const uint2*)(ubf + ra * 1024 + dblk + sg);
        ru1 = *(const uint2*)(ubf + rb2 * 1024 + dblk + sg);
        rB = *(const uint2*)(xdbc + (size_t)(m0 + bcr) * 64 + 32 + bne);
        if (PHASE == 2)
            rC = *(const uint2*)(xdbc + (size_t)(m0 + bcr) * 64 + 48 + bne);
    }

    for (int s = 0; s < 4; ++s) {
        const int lbase = s * 32;
        if (PHASE == 1 && s > 0) __syncthreads();
        // ---- regs -> LDS ----
        {
            const unsigned short* dp0 = (const unsigned short*)&rd0;
            const unsigned short* dp1 = (const unsigned short*)&rd1;
            const unsigned short* up0 = (const unsigned short*)&ru0;
            const unsigned short* up1 = (const unsigned short*)&ru1;
            const int l20 = sr >> 1, hh = (sr & 1) * 2;
            const int l21 = (16 + sr) >> 1;
#pragma unroll
            for (int j = 0; j < 4; ++j) {
                float d0 = bf2f(dp0[j]);
                float2 v0 = {d0, d0 * bf2f(up0[j])};
                *(float2*)&SDT[(sg + j) * 70 + l20 * 4 + hh] = v0;
                float d1 = bf2f(dp1[j]);
                float2 v1 = {d1, d1 * bf2f(up1[j])};
                *(float2*)&SDT[(sg + j) * 70 + l21 * 4 + hh] = v1;
            }
            const unsigned short* bb = (const unsigned short*)&rB;
            float4 bv = {bf2f(bb[0]), bf2f(bb[1]), bf2f(bb[2]), bf2f(bb[3])};
            *(float4*)&SB[bcr][bne] = bv;
            if (PHASE == 2) {
                const unsigned short* cp = (const unsigned short*)&rC;
                float4 cv = {bf2f(cp[0]), bf2f(cp[1]), bf2f(cp[2]), bf2f(cp[3])};
                *(float4*)&SC[bcr][bne] = cv;
            }
        }
        // ---- issue next sub-chunk loads ----
        if (s < 3) {
            const int nb = lbase + 32;
            size_t ra = (size_t)(m0 + nb + sr);
            size_t rb2 = (size_t)(m0 + nb + 16 + sr);
            rd0 = *(const uint2*)(dtp + ra * 1024 + dblk + sg);
            rd1 = *(const uint2*)(dtp + rb2 * 1024 + dblk + sg);
            ru0 = *(const uint2*)(ubf + ra * 1024 + dblk + sg);
            ru1 = *(const uint2*)(ubf + rb2 * 1024 + dblk + sg);
            rB = *(const uint2*)(xdbc + (size_t)(m0 + nb + bcr) * 64 + 32 + bne);
            if (PHASE == 2)
                rC = *(const uint2*)(xdbc + (size_t)(m0 + nb + bcr) * 64 + 48 + bne);
        }
        __syncthreads();

        // ---- scan 32 steps (16 l-pairs) ----
        for (int l2 = 0; l2 < 16; ++l2) {
            float4 sd = *(const float4*)&SDT[dl * 70 + l2 * 4];
            float4 B0 = *(const float4*)&SB[2 * l2][qq * 4];
            float4 B1 = *(const float4*)&SB[2 * l2 + 1][qq * 4];
            float p0 = 0.0f, p1 = 0.0f;
            float4 C0, C1;
            if (PHASE == 2) {
                C0 = *(const float4*)&SC[2 * l2][qq * 4];
                C1 = *(const float4*)&SC[2 * l2 + 1][qq * 4];
            }
            const float* B0p = (const float*)&B0;
            const float* B1p = (const float*)&B1;
            const float* C0p = (const float*)&C0;
            const float* C1p = (const float*)&C1;
#pragma unroll
            for (int j = 0; j < 4; ++j) {
                float e0 = __expf(sd.x * An[j]);
                if (PHASE == 1) prod[j] *= e0;
                h[j] = fmaf(e0, h[j], sd.y * B0p[j]);
                if (PHASE == 2) p0 = fmaf(h[j], C0p[j], p0);
                float e1 = __expf(sd.z * An[j]);
                if (PHASE == 1) prod[j] *= e1;
                h[j] = fmaf(e1, h[j], sd.w * B1p[j]);
                if (PHASE == 2) p1 = fmaf(h[j], C1p[j], p1);
            }
            if (PHASE == 2) {
                p0 += dpp_f<0xB1>(p0);
                p0 += dpp_f<0x4E>(p0);
                p1 += dpp_f<0xB1>(p1);
                p1 += dpp_f<0x4E>(p1);
                if (qq == 0) {
                    YS[2 * l2][dl] = p0;
                    YS[2 * l2 + 1][dl] = p1;
                }
            }
        }

        // ---- store y = (p + u*D) * silu(z), bf16 ----
        if (PHASE == 2) {
            __syncthreads();
            const int row = tid >> 2;            // 0..31
            const int d8 = (tid & 3) * 8;        // 8 d's
            size_t gr = (size_t)(m0 + lbase + row);
            float4 p40 = *(const float4*)&YS[row][d8];
            float4 p41 = *(const float4*)&YS[row][d8 + 4];
            uint4 uu = *(const uint4*)(ubf + gr * 1024 + dblk + d8);
            uint4 zz = *(const uint4*)(zbf + gr * 2048 + 1024 + dblk + d8);
            float4 D0 = *(const float4*)(Dp + dblk + d8);
            float4 D1 = *(const float4*)(Dp + dblk + d8 + 4);
            const unsigned short* up = (const unsigned short*)&uu;
            const unsigned short* zp = (const unsigned short*)&zz;
            const float* pp0 = (const float*)&p40;
            const float* pp1 = (const float*)&p41;
            const float* dd0 = (const float*)&D0;
            const float* dd1 = (const float*)&D1;
            union { unsigned short u[8]; uint4 v; } pk;
#pragma unroll
            for (int j = 0; j < 4; ++j) {
                float y = fmaf(bf2f(up[j]), dd0[j], pp0[j]) * siluf_(bf2f(zp[j]));
                pk.u[j] = f2bf(y);
            }
#pragma unroll
            for (int j = 0; j < 4; ++j) {
                float y = fmaf(bf2f(up[4 + j]), dd1[j], pp1[j]) * siluf_(bf2f(zp[4 + j]));
                pk.u[4 + j] = f2bf(y);
            }
            __syncthreads();   // YS consumed before next iter's writes
            *(uint4*)(ybf + gr * 1024 + dblk + d8) = pk.v;
        }
    }

    if (PHASE == 1) {
        float* hpo = hp + ((size_t)(b * 1024 + d)) * 256 + c * 32 + qq * 8;
        float4 o0 = {h[0], prod[0], h[1], prod[1]};
        float4 o1 = {h[2], prod[2], h[3], prod[3]};
        *(float4*)hpo = o0;
        *(float4*)(hpo + 4) = o1;
    }
}

// ---------------------------------------------------------------------------
extern "C" void kernel_launch(void* const* d_in, const int* in_sizes, int n_in,
                              void* d_out, int out_size, void* d_ws, size_t ws_size,
                              hipStream_t stream)
{
    const float* motion     = (const float*)d_in[0];
    const float* skip       = (const float*)d_in[1];
    const float* embed      = (const float*)d_in[2];
    const float* w_up       = (const float*)d_in[3];
    const float* b_up       = (const float*)d_in[4];
    const float* w1         = (const float*)d_in[5];
    const float* b1         = (const float*)d_in[6];
    const float* rms_w      = (const float*)d_in[7];
    const float* w2         = (const float*)d_in[8];
    const float* b2         = (const float*)d_in[9];
    const float* ln_w       = (const float*)d_in[10];
    const float* ln_b       = (const float*)d_in[11];
    const float* in_proj_w  = (const float*)d_in[12];
    const float* conv_w     = (const float*)d_in[13];
    const float* conv_b     = (const float*)d_in[14];
    const float* x_proj_w   = (const float*)d_in[15];
    const float* dt_proj_w  = (const float*)d_in[16];
    const float* dt_proj_b  = (const float*)d_in[17];
    const float* A_log      = (const float*)d_in[18];
    const float* D_param    = (const float*)d_in[19];
    const float* out_proj_w = (const float*)d_in[20];
    const float* out_proj_b = (const float*)d_in[21];
    const float* norm_f_w   = (const float*)d_in[22];
    const float* norm_f_b   = (const float*)d_in[23];
    float* out = (float*)d_out;
    float* ws = (float*)d_ws;

    float* xbuf = ws;                                        // (8192x512) f32
    float* xlnf = ws + 4194304;                              // (8192x512) f32
    unsigned short* xzbf  = (unsigned short*)(ws + 8388608); // (8192x2048) bf16
    unsigned short* ubf   = (unsigned short*)(ws + 16777216);// (8192x1024) bf16
    unsigned short* dtybf = (unsigned short*)(ws + 20971520);// (8192x1024) bf16
    unsigned short* xdbc  = (unsigned short*)(ws + 25165824);// (8192x64) bf16
    float* hp  = ws + 25427968;                              // 2M f
    unsigned short* xsbf = (unsigned short*)(ws + 29622272); // (8192x512) bf16
    unsigned short* mbf  = (unsigned short*)(ws + 31719424); // 2M bf16
    unsigned short* wupT = (unsigned short*)(ws + 32768000); // 512K bf16
    unsigned short* w1b  = (unsigned short*)(ws + 33030144); // 512K bf16
    unsigned short* w2b  = (unsigned short*)(ws + 33292288); // 256K bf16
    unsigned short* lw   = (unsigned short*)(ws + 33423360); // 4 x 1671168 bf16

    unsigned short* x0bf = xzbf;

    dim3 blk(256);

    prep_all<<<dim3(5696), blk, 0, stream>>>(
        motion, w_up, w1, w2, in_proj_w, out_proj_w, x_proj_w, dt_proj_w,
        mbf, wupT, w1b, w2b, lw);

    gemm_mfma64<0, false, false, true, true><<<dim3(1024), blk, 0, stream>>>(
        mbf, 512, wupT, 512, x0bf, 0, 1024, 512, 16, b_up, nullptr);
    concat_skip<<<dim3(2048), blk, 0, stream>>>(skip, x0bf);

    gemm_mfma64<0, false, false, false, false><<<dim3(1024), blk, 0, stream>>>(
        x0bf, 1024, w1b, 1024, xlnf, 512, 512, 1024, 8, b1, nullptr);
    rms_silu_k<<<dim3(2048), blk, 0, stream>>>(xlnf, xsbf, rms_w);

    gemm_mfma64<0, false, true, false, false><<<dim3(1024), blk, 0, stream>>>(
        xsbf, 512, w2b, 512, xbuf, 512, 512, 512, 8, b2, embed);

    for (int i = 0; i < 4; ++i) {
        unsigned short* ipw = lw + (size_t)i * 1671168;
        unsigned short* opw = ipw + 1048576;
        unsigned short* xpw = ipw + 1572864;
        unsigned short* wdt = ipw + 1638400;
        layernorm_k<true><<<dim3(2048), blk, 0, stream>>>(
            xbuf, xsbf, ln_w + (size_t)i * 512, ln_b + (size_t)i * 512);
        gemm_mfma<0, false, false, true><<<dim3(1024), blk, 0, stream>>>(
            xsbf, 512, ipw, 512, xzbf, 2048, 2048, 512, 16, nullptr, nullptr);
        conv_silu_k2<<<dim3(512), blk, 0, stream>>>(
            xzbf, ubf, conv_w + (size_t)i * 4096, conv_b + (size_t)i * 1024);
        gemm_xdbc<<<dim3(128), dim3(128), 0, stream>>>(ubf, xpw, xdbc);
        gemm_dt<<<dim3(512), blk, 0, stream>>>(
            xdbc, wdt, dt_proj_b + (size_t)i * 1024, dtybf);
        scan7<1><<<dim3(2048), dim3(128), 0, stream>>>(
            dtybf, ubf, nullptr, xdbc, xzbf, hp,
            A_log + (size_t)i * 16384, D_param + (size_t)i * 1024);
        scan7<2><<<dim3(2048), dim3(128), 0, stream>>>(
            dtybf, ubf, ubf, xdbc, xzbf, hp,
            A_log + (size_t)i * 16384, D_param + (size_t)i * 1024);
        gemm_mfma64<0, true, false, false, false><<<dim3(1024), blk, 0, stream>>>(
            ubf, 1024, opw, 1024, xbuf, 512, 512, 1024, 8,
            out_proj_b + (size_t)i * 512, nullptr);
    }

    layernorm_k<false><<<dim3(2048), blk, 0, stream>>>(xbuf, out, norm_f_w, norm_f_b);
}

// Round 11
// 690.799 us; speedup vs baseline: 1.0113x; 1.0057x over previous
//
#include <hip/hip_runtime.h>
#include <cstdint>
#include <cstddef>

#define DEV_INLINE __device__ __forceinline__

static constexpr float EPS = 1e-5f;

DEV_INLINE float sigmoidf_(float x) { return 1.0f / (1.0f + __expf(-x)); }
DEV_INLINE float siluf_(float x) { return x * sigmoidf_(x); }
DEV_INLINE float softplus_fast(float x) {
    return fmaxf(x, 0.0f) + __logf(1.0f + __expf(-fabsf(x)));
}
DEV_INLINE unsigned short f2bf(float x) {   // RNE f32 -> bf16
    unsigned u = __builtin_bit_cast(unsigned, x);
    u += 0x7FFFu + ((u >> 16) & 1u);
    return (unsigned short)(u >> 16);
}
DEV_INLINE float bf2f(unsigned short s) {
    unsigned u = ((unsigned)s) << 16;
    return __builtin_bit_cast(float, u);
}

typedef __attribute__((ext_vector_type(8))) short bf16x8;
typedef __attribute__((ext_vector_type(4))) float f32x4;

DEV_INLINE void gload16(const unsigned short* src, char* ldsdst) {
    __builtin_amdgcn_global_load_lds(
        (const __attribute__((address_space(1))) unsigned int*)src,
        (__attribute__((address_space(3))) unsigned int*)ldsdst, 16, 0, 0);
}

DEV_INLINE void cvt8(const float* __restrict__ s, unsigned short* __restrict__ d, int t) {
    float4 f0 = *(const float4*)(s + (size_t)t * 8);
    float4 f1 = *(const float4*)(s + (size_t)t * 8 + 4);
    union { unsigned short u[8]; uint4 v; } pk;
    pk.u[0] = f2bf(f0.x); pk.u[1] = f2bf(f0.y); pk.u[2] = f2bf(f0.z); pk.u[3] = f2bf(f0.w);
    pk.u[4] = f2bf(f1.x); pk.u[5] = f2bf(f1.y); pk.u[6] = f2bf(f1.z); pk.u[7] = f2bf(f1.w);
    *(uint4*)(d + (size_t)t * 8) = pk.v;
}

// ---------------------------------------------------------------------------
// One-shot prep: motion | w_upT | w1 | w2 | 4x layer weights | concat_skip.
// grid = 1024 + 1024 + 256 + 128 + 4*816 + 2048 = 7744
// ---------------------------------------------------------------------------
__global__ __launch_bounds__(256) void prep_all(
    const float* __restrict__ motion, const float* __restrict__ wup,
    const float* __restrict__ w1, const float* __restrict__ w2,
    const float* __restrict__ in_proj_w, const float* __restrict__ out_proj_w,
    const float* __restrict__ x_proj_w, const float* __restrict__ dt_proj_w,
    const float* __restrict__ skip,
    unsigned short* __restrict__ mbf, unsigned short* __restrict__ wupT,
    unsigned short* __restrict__ w1b, unsigned short* __restrict__ w2b,
    unsigned short* __restrict__ lw, unsigned short* __restrict__ x0)
{
    int bid = (int)blockIdx.x, tid = (int)threadIdx.x;
    if (bid < 1024) {
        cvt8(motion, mbf, bid * 256 + tid);
    } else if (bid < 2048) {
        int t = (bid - 1024) * 256 + tid;
        int c = t >> 9, o = t & 511;
        float2 v = *(const float2*)(wup + (size_t)t * 2);
        wupT[(size_t)o * 512 + c] = f2bf(v.x);
        wupT[262144 + (size_t)o * 512 + c] = f2bf(v.y);
    } else if (bid < 2304) {
        cvt8(w1, w1b, (bid - 2048) * 256 + tid);
    } else if (bid < 2432) {
        cvt8(w2, w2b, (bid - 2304) * 256 + tid);
    } else if (bid < 5696) {
        int r = bid - 2432;
        int layer = r / 816;
        int lb = r - layer * 816;
        unsigned short* base = lw + (size_t)layer * 1671168;
        if (lb < 512) {
            cvt8(in_proj_w + (size_t)layer * 1048576, base, lb * 256 + tid);
        } else if (lb < 768) {
            cvt8(out_proj_w + (size_t)layer * 524288, base + 1048576,
                 (lb - 512) * 256 + tid);
        } else if (lb < 800) {
            cvt8(x_proj_w + (size_t)layer * 65536, base + 1572864,
                 (lb - 768) * 256 + tid);
        } else {
            cvt8(dt_proj_w + (size_t)layer * 32768, base + 1638400,
                 (lb - 800) * 256 + tid);
        }
    } else {
        int t = (bid - 5696) * 256 + tid;   // concat skip -> x0 cols [512,1024)
        int row = t >> 6;
        int c8 = (t & 63) << 3;
        const float* s = skip + (size_t)row * 512 + c8;
        float4 f0 = *(const float4*)s;
        float4 f1 = *(const float4*)(s + 4);
        union { unsigned short u[8]; uint4 v; } pk;
        pk.u[0] = f2bf(f0.x); pk.u[1] = f2bf(f0.y); pk.u[2] = f2bf(f0.z); pk.u[3] = f2bf(f0.w);
        pk.u[4] = f2bf(f1.x); pk.u[5] = f2bf(f1.y); pk.u[6] = f2bf(f1.z); pk.u[7] = f2bf(f1.w);
        *(uint4*)(x0 + (size_t)row * 1024 + 512 + c8) = pk.v;
    }
}

// ---------------------------------------------------------------------------
// MFMA GEMM 128x128, counted-vmcnt pipeline (T3/T4): prefetch tile t+1 stays
// in flight across the barrier; wait only tile t's 8 loads (per wave).
// ---------------------------------------------------------------------------
template <int ACT, bool ACC, bool EMBED, bool OBF>
__global__ __launch_bounds__(256) void gemm_mfma(
    const unsigned short* __restrict__ A, int lda,
    const unsigned short* __restrict__ W, int ldw,
    void* __restrict__ Cv, int ldc, int N, int K, int gx,
    const float* __restrict__ bias, const float* __restrict__ embed)
{
    __shared__ unsigned short Asm[2][128 * 64];
    __shared__ unsigned short Wsm[2][128 * 64];
    const int tid = (int)threadIdx.x;
    const int lane = tid & 63;
    const int wv = tid >> 6;
    const int wm = wv >> 1, wn = wv & 1;

    const int nwg = (int)gridDim.x;
    const int lin = (int)blockIdx.x;
    const int logical = (lin & 7) * (nwg >> 3) + (lin >> 3);
    const int by = logical / gx;
    const int bx = logical - by * gx;
    const int bm = by * 128, bn = bx * 128;

    f32x4 acc[4][4] = {};
    const int l8 = lane >> 3;
    const int wc = lane & 7;
    const int wcg = wc ^ l8;
    const int NT = K >> 6;

    {
        char* aB = (char*)Asm[0];
        char* bB = (char*)Wsm[0];
#pragma unroll
        for (int i = 0; i < 4; ++i) {
            int rb = (i * 4 + wv) * 8;
            gload16(W + (size_t)(bn + rb + l8) * ldw + wcg * 8, bB + rb * 128);
            gload16(A + (size_t)(bm + rb + l8) * lda + wcg * 8, aB + rb * 128);
        }
    }

    for (int t = 0; t < NT; ++t) {
        const int cur = t & 1;
        if (t + 1 < NT) {
            const int k1 = (t + 1) << 6;
            char* aB = (char*)Asm[cur ^ 1];
            char* bB = (char*)Wsm[cur ^ 1];
#pragma unroll
            for (int i = 0; i < 4; ++i) {
                int rb = (i * 4 + wv) * 8;
                gload16(W + (size_t)(bn + rb + l8) * ldw + k1 + wcg * 8, bB + rb * 128);
                gload16(A + (size_t)(bm + rb + l8) * lda + k1 + wcg * 8, aB + rb * 128);
            }
            asm volatile("s_waitcnt vmcnt(8)" ::: "memory");
        } else {
            asm volatile("s_waitcnt vmcnt(0)" ::: "memory");
        }
        __builtin_amdgcn_s_barrier();          // tile t fully in LDS
        __builtin_amdgcn_sched_barrier(0);

        const char* aB = (const char*)Asm[cur];
        const char* bB = (const char*)Wsm[cur];
        const int rA = wm * 64 + (lane & 15);
        const int rB = wn * 64 + (lane & 15);
        const int q = lane >> 4;
#pragma unroll
        for (int kk = 0; kk < 2; ++kk) {
            bf16x8 af[4], bfr[4];
#pragma unroll
            for (int mi = 0; mi < 4; ++mi) {
                int row = rA + mi * 16;
                int ch = (kk * 4 + q) ^ (row & 7);
                af[mi] = *(const bf16x8*)(aB + row * 128 + ch * 16);
            }
#pragma unroll
            for (int ni = 0; ni < 4; ++ni) {
                int row = rB + ni * 16;
                int ch = (kk * 4 + q) ^ (row & 7);
                bfr[ni] = *(const bf16x8*)(bB + row * 128 + ch * 16);
            }
#pragma unroll
            for (int mi = 0; mi < 4; ++mi)
#pragma unroll
                for (int ni = 0; ni < 4; ++ni)
                    acc[mi][ni] = __builtin_amdgcn_mfma_f32_16x16x32_bf16(
                        af[mi], bfr[ni], acc[mi][ni], 0, 0, 0);
        }
        asm volatile("" ::: "memory");
        __builtin_amdgcn_s_barrier();          // buf[cur] free for next issue
        __builtin_amdgcn_sched_barrier(0);
    }

    const int cn = lane & 15;
    const int r0 = (lane >> 4) * 4;
    const int eb = EMBED ? (bm >> 10) * N : 0;
#pragma unroll
    for (int ni = 0; ni < 4; ++ni) {
        int col = bn + wn * 64 + ni * 16 + cn;
        float add = bias ? bias[col] : 0.0f;
        if (EMBED) add += embed[eb + col];
#pragma unroll
        for (int mi = 0; mi < 4; ++mi) {
#pragma unroll
            for (int r = 0; r < 4; ++r) {
                int row = bm + wm * 64 + mi * 16 + r0 + r;
                float v = acc[mi][ni][r] + add;
                if (ACT == 1) v = softplus_fast(v);
                if (OBF) {
                    ((unsigned short*)Cv)[(size_t)row * ldc + col] = f2bf(v);
                } else {
                    float* p = (float*)Cv + (size_t)row * ldc + col;
                    if (ACC) *p += v; else *p = v;
                }
            }
        }
    }
}

// ---------------------------------------------------------------------------
// MFMA GEMM 64x64, counted-vmcnt pipeline (4 loads/wave/tile). UPS epilogue.
// ---------------------------------------------------------------------------
template <int ACT, bool ACC, bool EMBED, bool OBF, bool UPS>
__global__ __launch_bounds__(256) void gemm_mfma64(
    const unsigned short* __restrict__ A, int lda,
    const unsigned short* __restrict__ W, int ldw,
    void* __restrict__ Cv, int ldc, int N, int K, int gx,
    const float* __restrict__ bias, const float* __restrict__ embed)
{
    __shared__ unsigned short Asm[2][64 * 64];
    __shared__ unsigned short Wsm[2][64 * 64];
    const int tid = (int)threadIdx.x;
    const int lane = tid & 63;
    const int wv = tid >> 6;
    const int wm = wv >> 1, wn = wv & 1;

    const int nwg = (int)gridDim.x;
    const int lin = (int)blockIdx.x;
    const int logical = (lin & 7) * (nwg >> 3) + (lin >> 3);
    const int by = logical / gx;
    const int bx = logical - by * gx;
    const int bm = by * 64, bn = bx * 64;

    f32x4 acc[2][2] = {};
    const int l8 = lane >> 3;
    const int wc = lane & 7;
    const int wcg = wc ^ l8;
    const int NT = K >> 6;

    {
        char* aB = (char*)Asm[0];
        char* bB = (char*)Wsm[0];
#pragma unroll
        for (int i = 0; i < 2; ++i) {
            int rb = (i * 4 + wv) * 8;
            gload16(W + (size_t)(bn + rb + l8) * ldw + wcg * 8, bB + rb * 128);
            gload16(A + (size_t)(bm + rb + l8) * lda + wcg * 8, aB + rb * 128);
        }
    }

    for (int t = 0; t < NT; ++t) {
        const int cur = t & 1;
        if (t + 1 < NT) {
            const int k1 = (t + 1) << 6;
            char* aB = (char*)Asm[cur ^ 1];
            char* bB = (char*)Wsm[cur ^ 1];
#pragma unroll
            for (int i = 0; i < 2; ++i) {
                int rb = (i * 4 + wv) * 8;
                gload16(W + (size_t)(bn + rb + l8) * ldw + k1 + wcg * 8, bB + rb * 128);
                gload16(A + (size_t)(bm + rb + l8) * lda + k1 + wcg * 8, aB + rb * 128);
            }
            asm volatile("s_waitcnt vmcnt(4)" ::: "memory");
        } else {
            asm volatile("s_waitcnt vmcnt(0)" ::: "memory");
        }
        __builtin_amdgcn_s_barrier();
        __builtin_amdgcn_sched_barrier(0);

        const char* aB = (const char*)Asm[cur];
        const char* bB = (const char*)Wsm[cur];
        const int rA = wm * 32 + (lane & 15);
        const int rB = wn * 32 + (lane & 15);
        const int q = lane >> 4;
#pragma unroll
        for (int kk = 0; kk < 2; ++kk) {
            bf16x8 af[2], bfr[2];
#pragma unroll
            for (int mi = 0; mi < 2; ++mi) {
                int row = rA + mi * 16;
                int ch = (kk * 4 + q) ^ (row & 7);
                af[mi] = *(const bf16x8*)(aB + row * 128 + ch * 16);
            }
#pragma unroll
            for (int ni = 0; ni < 2; ++ni) {
                int row = rB + ni * 16;
                int ch = (kk * 4 + q) ^ (row & 7);
                bfr[ni] = *(const bf16x8*)(bB + row * 128 + ch * 16);
            }
#pragma unroll
            for (int mi = 0; mi < 2; ++mi)
#pragma unroll
                for (int ni = 0; ni < 2; ++ni)
                    acc[mi][ni] = __builtin_amdgcn_mfma_f32_16x16x32_bf16(
                        af[mi], bfr[ni], acc[mi][ni], 0, 0, 0);
        }
        asm volatile("" ::: "memory");
        __builtin_amdgcn_s_barrier();
        __builtin_amdgcn_sched_barrier(0);
    }

    const int cn = lane & 15;
    const int r0 = (lane >> 4) * 4;
    const int eb = EMBED ? (bm >> 10) * N : 0;
#pragma unroll
    for (int ni = 0; ni < 2; ++ni) {
        int col = bn + wn * 32 + ni * 16 + cn;
        float add = bias ? bias[UPS ? (col & 511) : col] : 0.0f;
        if (EMBED) add += embed[eb + col];
#pragma unroll
        for (int mi = 0; mi < 2; ++mi) {
#pragma unroll
            for (int r = 0; r < 4; ++r) {
                int row = bm + wm * 32 + mi * 16 + r0 + r;
                float v = acc[mi][ni][r] + add;
                if (ACT == 1) v = softplus_fast(v);
                if (UPS) {
                    size_t ad = (size_t)row * 2048 + ((col >> 9) << 10) + (col & 511);
                    ((unsigned short*)Cv)[ad] = f2bf(v);
                } else if (OBF) {
                    ((unsigned short*)Cv)[(size_t)row * ldc + col] = f2bf(v);
                } else {
                    float* p = (float*)Cv + (size_t)row * ldc + col;
                    if (ACC) *p += v; else *p = v;
                }
            }
        }
    }
}

// ---------------------------------------------------------------------------
// dt GEMM: dt[8192,1024] = softplus(dtp[8192,32] @ dtw[1024,32]^T + bias)
// ---------------------------------------------------------------------------
__global__ __launch_bounds__(256) void gemm_dt(
    const unsigned short* __restrict__ xdbc,
    const unsigned short* __restrict__ wdt,
    const float* __restrict__ bias,
    unsigned short* __restrict__ out)
{
    __shared__ unsigned short S[128 * 136];
    const int tid = (int)threadIdx.x;
    const int lane = tid & 63;
    const int wv = tid >> 6;
    const int wm = wv >> 1, wn = wv & 1;

    const int lin = (int)blockIdx.x;
    const int logical = (lin & 7) * 64 + (lin >> 3);
    const int bm = (logical >> 3) * 128;
    const int bn = (logical & 7) * 128;

    const int fr = lane & 15;
    const int q = lane >> 4;

    bf16x8 af[4], wf[4];
#pragma unroll
    for (int mi = 0; mi < 4; ++mi)
        af[mi] = *(const bf16x8*)(xdbc + (size_t)(bm + wm * 64 + mi * 16 + fr) * 64 + q * 8);
#pragma unroll
    for (int ni = 0; ni < 4; ++ni)
        wf[ni] = *(const bf16x8*)(wdt + (size_t)(bn + wn * 64 + ni * 16 + fr) * 32 + q * 8);

    f32x4 acc[4][4] = {};
#pragma unroll
    for (int mi = 0; mi < 4; ++mi)
#pragma unroll
        for (int ni = 0; ni < 4; ++ni)
            acc[mi][ni] = __builtin_amdgcn_mfma_f32_16x16x32_bf16(
                af[mi], wf[ni], acc[mi][ni], 0, 0, 0);

    const int cn = lane & 15;
    const int r0 = (lane >> 4) * 4;
#pragma unroll
    for (int ni = 0; ni < 4; ++ni) {
        int lcol = wn * 64 + ni * 16 + cn;
        float add = bias[bn + lcol];
#pragma unroll
        for (int mi = 0; mi < 4; ++mi) {
#pragma unroll
            for (int r = 0; r < 4; ++r) {
                int lrow = wm * 64 + mi * 16 + r0 + r;
                S[lrow * 136 + lcol] = f2bf(softplus_fast(acc[mi][ni][r] + add));
            }
        }
    }
    __syncthreads();

    const int row = tid >> 1;
    const int half = tid & 1;
    const unsigned short* src = S + row * 136 + half * 64;
    unsigned short* dst = out + (size_t)(bm + row) * 1024 + bn + half * 64;
#pragma unroll
    for (int k = 0; k < 8; ++k) {
        uint4 v = *(const uint4*)(src + k * 8);
        *(uint4*)(dst + k * 8) = v;
    }
}

// ---------------------------------------------------------------------------
// Skinny MFMA GEMM: xdbc[M,64] = u[M,1024] * xpw[64,1024]^T (bf16 out)
// ---------------------------------------------------------------------------
__global__ __launch_bounds__(128) void gemm_xdbc(
    const unsigned short* __restrict__ A,
    const unsigned short* __restrict__ W,
    unsigned short* __restrict__ C)
{
    __shared__ unsigned short Asm[64 * 64];
    __shared__ unsigned short Wsm[64 * 64];
    const int tid = (int)threadIdx.x;
    const int lane = tid & 63;
    const int w = tid >> 6;
    const int bm = blockIdx.x * 64;
    const int l8 = lane >> 3, wc = lane & 7, wcg = wc ^ l8;
    char* aB = (char*)Asm;
    char* bB = (char*)Wsm;

    f32x4 acc[2][4] = {};

    for (int k0 = 0; k0 < 1024; k0 += 64) {
#pragma unroll
        for (int i = 0; i < 4; ++i) {
            int rb = (i * 2 + w) * 8;
            gload16(A + (size_t)(bm + rb + l8) * 1024 + k0 + wcg * 8, aB + rb * 128);
            gload16(W + (size_t)(rb + l8) * 1024 + k0 + wcg * 8, bB + rb * 128);
        }
        __syncthreads();
        const int rA = w * 32 + (lane & 15);
        const int rB = (lane & 15);
        const int q = lane >> 4;
#pragma unroll
        for (int kk = 0; kk < 2; ++kk) {
            bf16x8 af[2], bfr[4];
#pragma unroll
            for (int mi = 0; mi < 2; ++mi) {
                int row = rA + mi * 16;
                int ch = (kk * 4 + q) ^ (row & 7);
                af[mi] = *(const bf16x8*)(aB + row * 128 + ch * 16);
            }
#pragma unroll
            for (int ni = 0; ni < 4; ++ni) {
                int row = rB + ni * 16;
                int ch = (kk * 4 + q) ^ (row & 7);
                bfr[ni] = *(const bf16x8*)(bB + row * 128 + ch * 16);
            }
#pragma unroll
            for (int mi = 0; mi < 2; ++mi)
#pragma unroll
                for (int ni = 0; ni < 4; ++ni)
                    acc[mi][ni] = __builtin_amdgcn_mfma_f32_16x16x32_bf16(
                        af[mi], bfr[ni], acc[mi][ni], 0, 0, 0);
        }
        __syncthreads();
    }
    const int cn = lane & 15;
    const int r0 = (lane >> 4) * 4;
#pragma unroll
    for (int mi = 0; mi < 2; ++mi)
#pragma unroll
        for (int ni = 0; ni < 4; ++ni)
#pragma unroll
            for (int r = 0; r < 4; ++r) {
                int row = bm + w * 32 + mi * 16 + r0 + r;
                C[(size_t)row * 64 + ni * 16 + cn] = f2bf(acc[mi][ni][r]);
            }
}

// ---------------------------------------------------------------------------
template <bool BFOUT>
__global__ __launch_bounds__(256) void layernorm_k(
    const float* __restrict__ x, void* __restrict__ outp,
    const float* __restrict__ w, const float* __restrict__ b)
{
    const int row = blockIdx.x * 4 + ((int)threadIdx.x >> 6);
    const int lane = (int)threadIdx.x & 63;
    const float* xr = x + (size_t)row * 512;
    float4 v0 = *(const float4*)(xr + lane * 4);
    float4 v1 = *(const float4*)(xr + 256 + lane * 4);
    float s = v0.x + v0.y + v0.z + v0.w + v1.x + v1.y + v1.z + v1.w;
    float q = v0.x*v0.x + v0.y*v0.y + v0.z*v0.z + v0.w*v0.w
            + v1.x*v1.x + v1.y*v1.y + v1.z*v1.z + v1.w*v1.w;
#pragma unroll
    for (int o = 32; o; o >>= 1) {
        s += __shfl_xor(s, o, 64);
        q += __shfl_xor(q, o, 64);
    }
    const float mean = s * (1.0f / 512.0f);
    const float var = q * (1.0f / 512.0f) - mean * mean;
    const float rstd = rsqrtf(var + EPS);
    float4 w0 = *(const float4*)(w + lane * 4);
    float4 w1 = *(const float4*)(w + 256 + lane * 4);
    float4 b0 = *(const float4*)(b + lane * 4);
    float4 b1 = *(const float4*)(b + 256 + lane * 4);
    float4 o0, o1;
    o0.x = (v0.x - mean) * rstd * w0.x + b0.x;
    o0.y = (v0.y - mean) * rstd * w0.y + b0.y;
    o0.z = (v0.z - mean) * rstd * w0.z + b0.z;
    o0.w = (v0.w - mean) * rstd * w0.w + b0.w;
    o1.x = (v1.x - mean) * rstd * w1.x + b1.x;
    o1.y = (v1.y - mean) * rstd * w1.y + b1.y;
    o1.z = (v1.z - mean) * rstd * w1.z + b1.z;
    o1.w = (v1.w - mean) * rstd * w1.w + b1.w;
    if (BFOUT) {
        unsigned short* ob = (unsigned short*)outp + (size_t)row * 512;
        union { unsigned short u[4]; uint2 v; } p0, p1;
        p0.u[0] = f2bf(o0.x); p0.u[1] = f2bf(o0.y); p0.u[2] = f2bf(o0.z); p0.u[3] = f2bf(o0.w);
        p1.u[0] = f2bf(o1.x); p1.u[1] = f2bf(o1.y); p1.u[2] = f2bf(o1.z); p1.u[3] = f2bf(o1.w);
        *(uint2*)(ob + lane * 4) = p0.v;
        *(uint2*)(ob + 256 + lane * 4) = p1.v;
    } else {
        float* orow = (float*)outp + (size_t)row * 512;
        *(float4*)(orow + lane * 4) = o0;
        *(float4*)(orow + 256 + lane * 4) = o1;
    }
}

__global__ __launch_bounds__(256) void rms_silu_k(
    const float* __restrict__ x, unsigned short* __restrict__ o,
    const float* __restrict__ w)
{
    const int row = blockIdx.x * 4 + ((int)threadIdx.x >> 6);
    const int lane = (int)threadIdx.x & 63;
    const float* xr = x + (size_t)row * 512;
    float4 v0 = *(const float4*)(xr + lane * 4);
    float4 v1 = *(const float4*)(xr + 256 + lane * 4);
    float q = v0.x*v0.x + v0.y*v0.y + v0.z*v0.z + v0.w*v0.w
            + v1.x*v1.x + v1.y*v1.y + v1.z*v1.z + v1.w*v1.w;
#pragma unroll
    for (int of = 32; of; of >>= 1) q += __shfl_xor(q, of, 64);
    const float scale = rsqrtf(q * (1.0f / 512.0f) + EPS);
    float4 w0 = *(const float4*)(w + lane * 4);
    float4 w1 = *(const float4*)(w + 256 + lane * 4);
    union { unsigned short u[4]; uint2 v; } p0, p1;
    p0.u[0] = f2bf(siluf_(v0.x * scale * w0.x));
    p0.u[1] = f2bf(siluf_(v0.y * scale * w0.y));
    p0.u[2] = f2bf(siluf_(v0.z * scale * w0.z));
    p0.u[3] = f2bf(siluf_(v0.w * scale * w0.w));
    p1.u[0] = f2bf(siluf_(v1.x * scale * w1.x));
    p1.u[1] = f2bf(siluf_(v1.y * scale * w1.y));
    p1.u[2] = f2bf(siluf_(v1.z * scale * w1.z));
    p1.u[3] = f2bf(siluf_(v1.w * scale * w1.w));
    unsigned short* ob = o + (size_t)row * 512;
    *(uint2*)(ob + lane * 4) = p0.v;
    *(uint2*)(ob + 256 + lane * 4) = p1.v;
}

// ---------------------------------------------------------------------------
__global__ __launch_bounds__(256) void conv_silu_k2(
    const unsigned short* __restrict__ xz, unsigned short* __restrict__ ub,
    const float* __restrict__ cw, const float* __restrict__ cb)
{
    int t = blockIdx.x * 256 + (int)threadIdx.x;
    int d = t & 1023;
    int bc = t >> 10;
    int b = bc >> 4, ch = bc & 15;
    int l0 = ch * 64;
    float4 w4 = *(const float4*)(cw + (size_t)d * 4);
    float bias = cb[d];
    const unsigned short* src = xz + ((size_t)(b * 1024 + l0)) * 2048 + d;
    unsigned short* dst = ub + ((size_t)(b * 1024 + l0)) * 1024 + d;
    float x0 = 0.f, x1 = 0.f, x2 = 0.f;
    if (l0 > 0) {
        x0 = bf2f(src[-(size_t)3 * 2048]);
        x1 = bf2f(src[-(size_t)2 * 2048]);
        x2 = bf2f(src[-(size_t)1 * 2048]);
    }
    for (int l = 0; l < 64; ++l) {
        float x3 = bf2f(src[(size_t)l * 2048]);
        float v = fmaf(x0, w4.x, fmaf(x1, w4.y, fmaf(x2, w4.z, fmaf(x3, w4.w, bias))));
        dst[(size_t)l * 1024] = f2bf(siluf_(v));
        x0 = x1; x1 = x2; x2 = x3;
    }
}

// ---------------------------------------------------------------------------
// Split-L scan v7 (kept from round 10 — best measured variant).
// ---------------------------------------------------------------------------
template <int CTRL>
DEV_INLINE float dpp_f(float x) {
    int yi = __builtin_amdgcn_update_dpp(
        0, __builtin_bit_cast(int, x), CTRL, 0xF, 0xF, true);
    return __builtin_bit_cast(float, yi);
}

template <int PHASE>
__global__ __launch_bounds__(128) void scan7(
    const unsigned short* __restrict__ dtp,
    const unsigned short* ubf,
    unsigned short* ybf,
    const unsigned short* __restrict__ xdbc,
    const unsigned short* __restrict__ zbf,
    float* __restrict__ hp,
    const float* __restrict__ A_log,
    const float* __restrict__ Dp)
{
    __shared__ float SDT[32 * 70];
    __shared__ float SB[32][20];
    __shared__ float SC[PHASE == 2 ? 32 : 1][20];
    __shared__ float YS[PHASE == 2 ? 32 : 1][36];

    const int lin = (int)blockIdx.x;
    const int logical = (lin & 7) * 256 + (lin >> 3);
    const int g = logical & 31;
    const int r = logical >> 5;
    const int c = r & 7, b = r >> 3;
    if (PHASE == 1 && c == 7) return;
    const int tid = (int)threadIdx.x;
    const int dl = tid >> 2, qq = tid & 3;
    const int dblk = g << 5;
    const int d = dblk + dl;
    const int m0 = b * 1024 + c * 128;

    float An[4];
#pragma unroll
    for (int j = 0; j < 4; ++j)
        An[j] = -__expf(A_log[(size_t)d * 16 + qq * 4 + j]);

    float h[4] = {};
    float prod[4] = {1.f, 1.f, 1.f, 1.f};
    if (PHASE == 2) {
        const float* hpb = hp + ((size_t)(b * 1024 + d)) * 256 + qq * 8;
        for (int cc = 0; cc < c; ++cc) {
            float4 v0 = *(const float4*)(hpb + cc * 32);
            float4 v1 = *(const float4*)(hpb + cc * 32 + 4);
            h[0] = fmaf(v0.y, h[0], v0.x);
            h[1] = fmaf(v0.w, h[1], v0.z);
            h[2] = fmaf(v1.y, h[2], v1.x);
            h[3] = fmaf(v1.w, h[3], v1.z);
        }
    }

    const int sr = tid >> 3;
    const int sg = (tid & 7) * 4;
    const int bcr = tid >> 2;
    const int bne = (tid & 3) << 2;

    uint2 rd0, rd1, ru0, ru1, rB, rC;

    {
        size_t ra = (size_t)(m0 + sr);
        size_t rb2 = (size_t)(m0 + 16 + sr);
        rd0 = *(const uint2*)(dtp + ra * 1024 + dblk + sg);
        rd1 = *(const uint2*)(dtp + rb2 * 1024 + dblk + sg);
        ru0 = *(const uint2*)(ubf + ra * 1024 + dblk + sg);
        ru1 = *(const uint2*)(ubf + rb2 * 1024 + dblk + sg);
        rB = *(const uint2*)(xdbc + (size_t)(m0 + bcr) * 64 + 32 + bne);
        if (PHASE == 2)
            rC = *(const uint2*)(xdbc + (size_t)(m0 + bcr) * 64 + 48 + bne);
    }

    for (int s = 0; s < 4; ++s) {
        const int lbase = s * 32;
        if (PHASE == 1 && s > 0) __syncthreads();
        {
            const unsigned short* dp0 = (const unsigned short*)&rd0;
            const unsigned short* dp1 = (const unsigned short*)&rd1;
            const unsigned short* up0 = (const unsigned short*)&ru0;
            const unsigned short* up1 = (const unsigned short*)&ru1;
            const int l20 = sr >> 1, hh = (sr & 1) * 2;
            const int l21 = (16 + sr) >> 1;
#pragma unroll
            for (int j = 0; j < 4; ++j) {
                float d0 = bf2f(dp0[j]);
                float2 v0 = {d0, d0 * bf2f(up0[j])};
                *(float2*)&SDT[(sg + j) * 70 + l20 * 4 + hh] = v0;
                float d1 = bf2f(dp1[j]);
                float2 v1 = {d1, d1 * bf2f(up1[j])};
                *(float2*)&SDT[(sg + j) * 70 + l21 * 4 + hh] = v1;
            }
            const unsigned short* bb = (const unsigned short*)&rB;
            float4 bv = {bf2f(bb[0]), bf2f(bb[1]), bf2f(bb[2]), bf2f(bb[3])};
            *(float4*)&SB[bcr][bne] = bv;
            if (PHASE == 2) {
                const unsigned short* cp = (const unsigned short*)&rC;
                float4 cv = {bf2f(cp[0]), bf2f(cp[1]), bf2f(cp[2]), bf2f(cp[3])};
                *(float4*)&SC[bcr][bne] = cv;
            }
        }
        if (s < 3) {
            const int nb = lbase + 32;
            size_t ra = (size_t)(m0 + nb + sr);
            size_t rb2 = (size_t)(m0 + nb + 16 + sr);
            rd0 = *(const uint2*)(dtp + ra * 1024 + dblk + sg);
            rd1 = *(const uint2*)(dtp + rb2 * 1024 + dblk + sg);
            ru0 = *(const uint2*)(ubf + ra * 1024 + dblk + sg);
            ru1 = *(const uint2*)(ubf + rb2 * 1024 + dblk + sg);
            rB = *(const uint2*)(xdbc + (size_t)(m0 + nb + bcr) * 64 + 32 + bne);
            if (PHASE == 2)
                rC = *(const uint2*)(xdbc + (size_t)(m0 + nb + bcr) * 64 + 48 + bne);
        }
        __syncthreads();

        for (int l2 = 0; l2 < 16; ++l2) {
            float4 sd = *(const float4*)&SDT[dl * 70 + l2 * 4];
            float4 B0 = *(const float4*)&SB[2 * l2][qq * 4];
            float4 B1 = *(const float4*)&SB[2 * l2 + 1][qq * 4];
            float p0 = 0.0f, p1 = 0.0f;
            float4 C0, C1;
            if (PHASE == 2) {
                C0 = *(const float4*)&SC[2 * l2][qq * 4];
                C1 = *(const float4*)&SC[2 * l2 + 1][qq * 4];
            }
            const float* B0p = (const float*)&B0;
            const float* B1p = (const float*)&B1;
            const float* C0p = (const float*)&C0;
            const float* C1p = (const float*)&C1;
#pragma unroll
            for (int j = 0; j < 4; ++j) {
                float e0 = __expf(sd.x * An[j]);
                if (PHASE == 1) prod[j] *= e0;
                h[j] = fmaf(e0, h[j], sd.y * B0p[j]);
                if (PHASE == 2) p0 = fmaf(h[j], C0p[j], p0);
                float e1 = __expf(sd.z * An[j]);
                if (PHASE == 1) prod[j] *= e1;
                h[j] = fmaf(e1, h[j], sd.w * B1p[j]);
                if (PHASE == 2) p1 = fmaf(h[j], C1p[j], p1);
            }
            if (PHASE == 2) {
                p0 += dpp_f<0xB1>(p0);
                p0 += dpp_f<0x4E>(p0);
                p1 += dpp_f<0xB1>(p1);
                p1 += dpp_f<0x4E>(p1);
                if (qq == 0) {
                    YS[2 * l2][dl] = p0;
                    YS[2 * l2 + 1][dl] = p1;
                }
            }
        }

        if (PHASE == 2) {
            __syncthreads();
            const int row = tid >> 2;
            const int d8 = (tid & 3) * 8;
            size_t gr = (size_t)(m0 + lbase + row);
            float4 p40 = *(const float4*)&YS[row][d8];
            float4 p41 = *(const float4*)&YS[row][d8 + 4];
            uint4 uu = *(const uint4*)(ubf + gr * 1024 + dblk + d8);
            uint4 zz = *(const uint4*)(zbf + gr * 2048 + 1024 + dblk + d8);
            float4 D0 = *(const float4*)(Dp + dblk + d8);
            float4 D1 = *(const float4*)(Dp + dblk + d8 + 4);
            const unsigned short* up = (const unsigned short*)&uu;
            const unsigned short* zp = (const unsigned short*)&zz;
            const float* pp0 = (const float*)&p40;
            const float* pp1 = (const float*)&p41;
            const float* dd0 = (const float*)&D0;
            const float* dd1 = (const float*)&D1;
            union { unsigned short u[8]; uint4 v; } pk;
#pragma unroll
            for (int j = 0; j < 4; ++j) {
                float y = fmaf(bf2f(up[j]), dd0[j], pp0[j]) * siluf_(bf2f(zp[j]));
                pk.u[j] = f2bf(y);
            }
#pragma unroll
            for (int j = 0; j < 4; ++j) {
                float y = fmaf(bf2f(up[4 + j]), dd1[j], pp1[j]) * siluf_(bf2f(zp[4 + j]));
                pk.u[4 + j] = f2bf(y);
            }
            __syncthreads();
            *(uint4*)(ybf + gr * 1024 + dblk + d8) = pk.v;
        }
    }

    if (PHASE == 1) {
        float* hpo = hp + ((size_t)(b * 1024 + d)) * 256 + c * 32 + qq * 8;
        float4 o0 = {h[0], prod[0], h[1], prod[1]};
        float4 o1 = {h[2], prod[2], h[3], prod[3]};
        *(float4*)hpo = o0;
        *(float4*)(hpo + 4) = o1;
    }
}

// ---------------------------------------------------------------------------
extern "C" void kernel_launch(void* const* d_in, const int* in_sizes, int n_in,
                              void* d_out, int out_size, void* d_ws, size_t ws_size,
                              hipStream_t stream)
{
    const float* motion     = (const float*)d_in[0];
    const float* skip       = (const float*)d_in[1];
    const float* embed      = (const float*)d_in[2];
    const float* w_up       = (const float*)d_in[3];
    const float* b_up       = (const float*)d_in[4];
    const float* w1         = (const float*)d_in[5];
    const float* b1         = (const float*)d_in[6];
    const float* rms_w      = (const float*)d_in[7];
    const float* w2         = (const float*)d_in[8];
    const float* b2         = (const float*)d_in[9];
    const float* ln_w       = (const float*)d_in[10];
    const float* ln_b       = (const float*)d_in[11];
    const float* in_proj_w  = (const float*)d_in[12];
    const float* conv_w     = (const float*)d_in[13];
    const float* conv_b     = (const float*)d_in[14];
    const float* x_proj_w   = (const float*)d_in[15];
    const float* dt_proj_w  = (const float*)d_in[16];
    const float* dt_proj_b  = (const float*)d_in[17];
    const float* A_log      = (const float*)d_in[18];
    const float* D_param    = (const float*)d_in[19];
    const float* out_proj_w = (const float*)d_in[20];
    const float* out_proj_b = (const float*)d_in[21];
    const float* norm_f_w   = (const float*)d_in[22];
    const float* norm_f_b   = (const float*)d_in[23];
    float* out = (float*)d_out;
    float* ws = (float*)d_ws;

    float* xbuf = ws;                                        // (8192x512) f32
    float* xlnf = ws + 4194304;                              // (8192x512) f32
    unsigned short* xzbf  = (unsigned short*)(ws + 8388608); // (8192x2048) bf16
    unsigned short* ubf   = (unsigned short*)(ws + 16777216);// (8192x1024) bf16
    unsigned short* dtybf = (unsigned short*)(ws + 20971520);// (8192x1024) bf16
    unsigned short* xdbc  = (unsigned short*)(ws + 25165824);// (8192x64) bf16
    float* hp  = ws + 25427968;                              // 2M f
    unsigned short* xsbf = (unsigned short*)(ws + 29622272); // (8192x512) bf16
    unsigned short* mbf  = (unsigned short*)(ws + 31719424); // 2M bf16
    unsigned short* wupT = (unsigned short*)(ws + 32768000); // 512K bf16
    unsigned short* w1b  = (unsigned short*)(ws + 33030144); // 512K bf16
    unsigned short* w2b  = (unsigned short*)(ws + 33292288); // 256K bf16
    unsigned short* lw   = (unsigned short*)(ws + 33423360); // 4 x 1671168 bf16

    unsigned short* x0bf = xzbf;

    dim3 blk(256);

    prep_all<<<dim3(7744), blk, 0, stream>>>(
        motion, w_up, w1, w2, in_proj_w, out_proj_w, x_proj_w, dt_proj_w,
        skip, mbf, wupT, w1b, w2b, lw, x0bf);

    gemm_mfma64<0, false, false, true, true><<<dim3(1024), blk, 0, stream>>>(
        mbf, 512, wupT, 512, x0bf, 0, 1024, 512, 16, b_up, nullptr);

    gemm_mfma64<0, false, false, false, false><<<dim3(1024), blk, 0, stream>>>(
        x0bf, 1024, w1b, 1024, xlnf, 512, 512, 1024, 8, b1, nullptr);
    rms_silu_k<<<dim3(2048), blk, 0, stream>>>(xlnf, xsbf, rms_w);

    gemm_mfma64<0, false, true, false, false><<<dim3(1024), blk, 0, stream>>>(
        xsbf, 512, w2b, 512, xbuf, 512, 512, 512, 8, b2, embed);

    for (int i = 0; i < 4; ++i) {
        unsigned short* ipw = lw + (size_t)i * 1671168;
        unsigned short* opw = ipw + 1048576;
        unsigned short* xpw = ipw + 1572864;
        unsigned short* wdt = ipw + 1638400;
        layernorm_k<true><<<dim3(2048), blk, 0, stream>>>(
            xbuf, xsbf, ln_w + (size_t)i * 512, ln_b + (size_t)i * 512);
        gemm_mfma<0, false, false, true><<<dim3(1024), blk, 0, stream>>>(
            xsbf, 512, ipw, 512, xzbf, 2048, 2048, 512, 16, nullptr, nullptr);
        conv_silu_k2<<<dim3(512), blk, 0, stream>>>(
            xzbf, ubf, conv_w + (size_t)i * 4096, conv_b + (size_t)i * 1024);
        gemm_xdbc<<<dim3(128), dim3(128), 0, stream>>>(ubf, xpw, xdbc);
        gemm_dt<<<dim3(512), blk, 0, stream>>>(
            xdbc, wdt, dt_proj_b + (size_t)i * 1024, dtybf);
        scan7<1><<<dim3(2048), dim3(128), 0, stream>>>(
            dtybf, ubf, nullptr, xdbc, xzbf, hp,
            A_log + (size_t)i * 16384, D_param + (size_t)i * 1024);
        scan7<2><<<dim3(2048), dim3(128), 0, stream>>>(
            dtybf, ubf, ubf, xdbc, xzbf, hp,
            A_log + (size_t)i * 16384, D_param + (size_t)i * 1024);
        gemm_mfma64<0, true, false, false, false><<<dim3(1024), blk, 0, stream>>>(
            ubf, 1024, opw, 1024, xbuf, 512, 512, 1024, 8,
            out_proj_b + (size_t)i * 512, nullptr);
    }

    layernorm_k<false><<<dim3(2048), blk, 0, stream>>>(xbuf, out, norm_f_w, norm_f_b);
}